// Round 15
// baseline (261.310 us; speedup 1.0000x reference)
//
#include <hip/hip_runtime.h>
#include <hip/hip_bf16.h>
#include <hip/hip_fp16.h>

// ---------------------------------------------------------------------------
// GAT link predictor: 2x GATConv + pair MLP.
// R15: zero-free + atomic-free CSR build (passA raw counts; scanb2 does
//      block-prefix-per-bucket in place + bucket scan); node_mlp fused into
//      edge2 (LDS-broadcast projection, hf buffer deleted). 9 launches.
//      MFMA f16 GEMMs, fp16 gather tables, 32-slot+tail edge1.
// ---------------------------------------------------------------------------

#define LRELU_SLOPE 0.2f
#define BKT_SH 7
#define NB_MAX 512

typedef _Float16 v8h __attribute__((ext_vector_type(8)));
typedef float    v4f __attribute__((ext_vector_type(4)));

// ---- weight prep (no zeroing needed anywhere) ----
__global__ void __launch_bounds__(256) prep_kernel(
    const float* __restrict__ W1, const float* __restrict__ W2,
    const float* __restrict__ Wm1,
    _Float16* __restrict__ W1Th, _Float16* __restrict__ W2Th,
    float* __restrict__ Wm1T)
{
    int i = blockIdx.x * 256 + threadIdx.x;
    if (i < 16384) {                       // W1 [128][128] -> W1Th [128][128]
        int k = i >> 7, j = i & 127;
        W1Th[j * 128 + k] = (_Float16)W1[i];
    } else if (i < 16384 + 8192) {         // W2 [128][64] -> W2Th [64][128]
        int t = i - 16384;
        int k = t >> 6, j = t & 63;
        W2Th[j * 128 + k] = (_Float16)W2[t];
    } else if (i < 16384 + 8192 + 4096) {  // Wm1 [128][32] -> Wm1T [32][128]
        int t = i - 24576;
        int k = t >> 5, j = t & 31;
        Wm1T[j * 128 + k] = Wm1[t];
    }
}

// ---- MFMA f16 GEMM + fused attention scores (device body) ----
template<int AHALF>
__device__ __forceinline__ void gemm_att_body(
    int bx, int by,
    const void* __restrict__ Xv, const _Float16* __restrict__ WTH,
    const float* __restrict__ atts, const float* __restrict__ attd,
    _Float16* __restrict__ OUT, float* __restrict__ oas, float* __restrict__ oad,
    int N, int ncols, int H, int headShift)
{
    __shared__ _Float16 cs[64 * 68];
    int tid = threadIdx.x;
    int lane = tid & 63;
    int wv = tid >> 6;
    int rowBase = bx * 64 + wv * 16;
    int colBase = by * 64;
    int lr = lane & 15;
    int lk = lane >> 4;

    v8h bf[4][4];
    #pragma unroll
    for (int ct = 0; ct < 4; ct++) {
        const _Float16* bp = WTH + (size_t)(colBase + ct * 16 + lr) * 128 + lk * 8;
        #pragma unroll
        for (int ks = 0; ks < 4; ks++)
            bf[ct][ks] = *(const v8h*)(bp + ks * 32);
    }

    int arow = rowBase + lr;
    if (arow >= N) arow = N - 1;            // clamp; stores masked below
    v4f acc[4];
    #pragma unroll
    for (int ct = 0; ct < 4; ct++) acc[ct] = (v4f){0.f, 0.f, 0.f, 0.f};

    if (AHALF) {
        const _Float16* ap = (const _Float16*)Xv + (size_t)arow * 128 + lk * 8;
        #pragma unroll
        for (int ks = 0; ks < 4; ks++) {
            v8h af = *(const v8h*)(ap + ks * 32);
            #pragma unroll
            for (int ct = 0; ct < 4; ct++)
                acc[ct] = __builtin_amdgcn_mfma_f32_16x16x32_f16(af, bf[ct][ks],
                                                                 acc[ct], 0, 0, 0);
        }
    } else {
        const float* ap = (const float*)Xv + (size_t)arow * 128 + lk * 8;
        #pragma unroll
        for (int ks = 0; ks < 4; ks++) {
            float4 a0 = *(const float4*)(ap + ks * 32);
            float4 a1 = *(const float4*)(ap + ks * 32 + 4);
            v8h af;
            af[0] = (_Float16)a0.x; af[1] = (_Float16)a0.y;
            af[2] = (_Float16)a0.z; af[3] = (_Float16)a0.w;
            af[4] = (_Float16)a1.x; af[5] = (_Float16)a1.y;
            af[6] = (_Float16)a1.z; af[7] = (_Float16)a1.w;
            #pragma unroll
            for (int ct = 0; ct < 4; ct++)
                acc[ct] = __builtin_amdgcn_mfma_f32_16x16x32_f16(af, bf[ct][ks],
                                                                 acc[ct], 0, 0, 0);
        }
    }

    int ctPerHead = (1 << headShift) >> 4;        // 2 (L1) or 4 (L2)
    #pragma unroll
    for (int hh = 0; hh < 2; hh++) {
        if (hh * ctPerHead >= 4) break;
        float ps[4] = {0.f, 0.f, 0.f, 0.f};
        float pd[4] = {0.f, 0.f, 0.f, 0.f};
        for (int c2 = 0; c2 < ctPerHead; c2++) {
            int ct = hh * ctPerHead + c2;
            int col = colBase + ct * 16 + lr;
            float ws = atts[col], wd = attd[col];
            #pragma unroll
            for (int r = 0; r < 4; r++) {
                ps[r] = fmaf(acc[ct][r], ws, ps[r]);
                pd[r] = fmaf(acc[ct][r], wd, pd[r]);
            }
        }
        #pragma unroll
        for (int r = 0; r < 4; r++) {
            #pragma unroll
            for (int m = 1; m < 16; m <<= 1) {
                ps[r] += __shfl_xor(ps[r], m);
                pd[r] += __shfl_xor(pd[r], m);
            }
        }
        if (lr == 0) {
            int head = (colBase >> headShift) + hh;
            #pragma unroll
            for (int r = 0; r < 4; r++) {
                int row = rowBase + lk * 4 + r;
                if (row < N) {
                    oas[(size_t)row * H + head] = ps[r];
                    oad[(size_t)row * H + head] = pd[r];
                }
            }
        }
    }

    #pragma unroll
    for (int ct = 0; ct < 4; ct++)
        #pragma unroll
        for (int r = 0; r < 4; r++)
            cs[(wv * 16 + lk * 4 + r) * 68 + ct * 16 + lr] = (_Float16)acc[ct][r];
    __syncthreads();
    int rr = tid >> 2;
    int cb = (tid & 3) * 16;
    int grow = bx * 64 + rr;
    if (grow < N) {
        const uint4* sp = (const uint4*)(cs + rr * 68 + cb);
        _Float16* op = OUT + (size_t)grow * ncols + colBase + cb;
        uint4 w0 = sp[0];
        uint4 w1 = sp[1];
        *(uint4*)op = w0;
        *(uint4*)(op + 8) = w1;
    }
}

// ---- passA body: LDS bucket histogram -> raw per-(block,bucket) counts ----
__device__ __forceinline__ void passA_body(
    int blk, const int* __restrict__ src, const int* __restrict__ dst,
    int E, int N, int* __restrict__ lcnt_g, int nbkt)
{
    __shared__ int lcnt[NB_MAX];
    int tid = threadIdx.x;
    int EN = E + N;
    int base = blk * 4096;
    for (int b = tid; b < nbkt; b += 256) lcnt[b] = 0;
    __syncthreads();
    #pragma unroll
    for (int j = 0; j < 16; j++) {
        int i = base + j * 256 + tid;
        if (i < EN) {
            int d = (i < E) ? dst[i] : (i - E);
            atomicAdd(&lcnt[d >> BKT_SH], 1);
        }
    }
    __syncthreads();
    for (int b = tid; b < nbkt; b += 256)
        lcnt_g[(size_t)blk * nbkt + b] = lcnt[b];
}

// ---- fused: gemm1 (blocks [0, 2*nbG)) || passA (rest) ----
__global__ void __launch_bounds__(256) gemm1_passA_kernel(
    const float* __restrict__ X, const _Float16* __restrict__ WTH,
    const float* __restrict__ atts, const float* __restrict__ attd,
    _Float16* __restrict__ OUT, float* __restrict__ oas, float* __restrict__ oad,
    int N, int nbG,
    const int* __restrict__ src, const int* __restrict__ dst, int E,
    int* __restrict__ lcnt_g, int nbkt)
{
    if ((int)blockIdx.x < 2 * nbG) {
        gemm_att_body<0>(blockIdx.x % nbG, blockIdx.x / nbG, X, WTH, atts, attd,
                         OUT, oas, oad, N, 128, 4, 5);
    } else {
        passA_body((int)blockIdx.x - 2 * nbG, src, dst, E, N, lcnt_g, nbkt);
    }
}

__global__ void __launch_bounds__(256) gemm2_kernel(
    const _Float16* __restrict__ X, const _Float16* __restrict__ WTH,
    const float* __restrict__ atts, const float* __restrict__ attd,
    _Float16* __restrict__ OUT, float* __restrict__ oas, float* __restrict__ oad,
    int N)
{
    gemm_att_body<1>(blockIdx.x, 0, X, WTH, atts, attd, OUT, oas, oad,
                     N, 64, 1, 6);
}

// ---- scanb2: per-bucket block-prefix in place + bucket scan -> bktoff ----
// thread t owns bucket t: loop blocks, replace count with exclusive prefix;
// then scan bucket totals across the 391 buckets.
__global__ void __launch_bounds__(512) scanb2_kernel(
    int* __restrict__ lcnt_g, int* __restrict__ bktoff, int nbkt, int nbA)
{
    __shared__ int wsum[8];
    int t = threadIdx.x;
    int cum = 0;
    if (t < nbkt) {
        for (int blk = 0; blk < nbA; ++blk) {
            size_t idx = (size_t)blk * nbkt + t;
            int v = lcnt_g[idx];
            lcnt_g[idx] = cum;          // exclusive block-prefix for bucket t
            cum += v;
        }
    }
    int lane = t & 63, wid = t >> 6;
    int v = (t < nbkt) ? cum : 0;
    #pragma unroll
    for (int off = 1; off < 64; off <<= 1) {
        int y = __shfl_up(v, off);
        if (lane >= off) v += y;
    }
    if (lane == 63) wsum[wid] = v;
    __syncthreads();
    if (wid == 0) {
        int s = (lane < 8) ? wsum[lane] : 0;
        #pragma unroll
        for (int off = 1; off < 8; off <<= 1) {
            int y = __shfl_up(s, off);
            if (lane >= off) s += y;
        }
        if (lane < 8) wsum[lane] = s;
    }
    __syncthreads();
    if (wid > 0) v += wsum[wid - 1];
    if (t < nbkt) bktoff[t + 1] = v;
    if (t == 0) bktoff[0] = 0;
}

// ---- passB: write bucket-major (d,s) runs via LDS cursors ----
__global__ void __launch_bounds__(256) passB_kernel(
    const int* __restrict__ src, const int* __restrict__ dst, int E, int N,
    const int* __restrict__ bktoff, const int* __restrict__ lcnt_g,
    uint2* __restrict__ ebuf, int nbkt)
{
    __shared__ int sbase[NB_MAX];
    __shared__ int loff[NB_MAX];
    int blk = blockIdx.x;
    int tid = threadIdx.x;
    int EN = E + N;
    int base = blk * 4096;
    for (int b = tid; b < nbkt; b += 256) {
        sbase[b] = bktoff[b] + lcnt_g[(size_t)blk * nbkt + b];
        loff[b] = 0;
    }
    __syncthreads();
    #pragma unroll
    for (int j = 0; j < 16; j++) {
        int i = base + j * 256 + tid;
        if (i < EN) {
            int s, d;
            if (i < E) { s = src[i]; d = dst[i]; } else { s = d = i - E; }
            int b = d >> BKT_SH;
            int off = atomicAdd(&loff[b], 1);
            ebuf[(size_t)sbase[b] + off] = make_uint2((unsigned)d, (unsigned)s);
        }
    }
}

// ---- build: per-bucket node hist + in-block scan -> rowp + csrs ----
__global__ void __launch_bounds__(256) build_kernel(
    const uint2* __restrict__ ebuf, const int* __restrict__ bktoff,
    int* __restrict__ rowp, int* __restrict__ csrs, int N, int nbkt)
{
    __shared__ int ldeg[128];
    __shared__ int lrow[129];
    __shared__ int lcur[128];
    __shared__ int w0tot;
    int b = blockIdx.x;
    if (b >= nbkt) return;
    int n0 = b << BKT_SH;
    int n1 = n0 + 128; if (n1 > N) n1 = N;
    int r0 = bktoff[b], r1 = bktoff[b + 1];
    int t = threadIdx.x;
    if (t < 128) { ldeg[t] = 0; lcur[t] = 0; }
    __syncthreads();
    for (int i = r0 + t; i < r1; i += 256)
        atomicAdd(&ldeg[(int)ebuf[i].x - n0], 1);
    __syncthreads();
    int lane = t & 63;
    int v = (t < 128) ? ldeg[t] : 0;
    #pragma unroll
    for (int off = 1; off < 64; off <<= 1) {
        int y = __shfl_up(v, off);
        if (lane >= off) v += y;
    }
    if (t == 63) w0tot = v;
    __syncthreads();
    if (t >= 64 && t < 128) v += w0tot;
    if (t < 128) lrow[t + 1] = v;
    if (t == 0) { lrow[0] = 0; rowp[n0] = r0; }
    if (t < n1 - n0) rowp[n0 + t + 1] = r0 + v;
    __syncthreads();
    for (int i = r0 + t; i < r1; i += 256) {
        uint2 e = ebuf[i];
        int d = (int)e.x - n0;
        int pos = r0 + lrow[d] + atomicAdd(&lcur[d], 1);
        csrs[pos] = (int)e.y;
    }
}

// ---- edge1 chunk: K-slot staged gather + FMA (padding clamps/zeros) ----
template<int K>
__device__ __forceinline__ void chunk1(
    const int* __restrict__ csr, int base, int cnt,
    const float* __restrict__ as1, float adv,
    int el, int hh, int hd, int lane, const __half2* __restrict__ h1,
    float& accx, float& accy, float& srun)
{
    float wvA = 0.f, wvB = 0.f;
    if (el < cnt) {
        int s = csr[base + el];
        float e = as1[s * 4 + hh] + adv;
        e = e > 0.f ? e : LRELU_SLOPE * e;
        wvA = __expf(e);
    }
    if (K > 16 && el + 16 < cnt) {
        int s = csr[base + 16 + el];
        float e = as1[s * 4 + hh] + adv;
        e = e > 0.f ? e : LRELU_SLOPE * e;
        wvB = __expf(e);
    }
    float t = wvA + wvB;
    t += __shfl_xor(t, 4);  t += __shfl_xor(t, 8);
    t += __shfl_xor(t, 16); t += __shfl_xor(t, 32);
    srun += t;
    __half2 hv[K];
    #pragma unroll
    for (int e2 = 0; e2 < K; ++e2) {
        int ee = e2 < cnt ? e2 : cnt - 1;      // wave-uniform clamp
        int s = csr[base + ee];                // uniform -> s_load
        hv[e2] = h1[(size_t)s * 64 + lane];
    }
    #pragma unroll
    for (int e2 = 0; e2 < K; ++e2) {
        float av = (e2 < 16) ? __shfl(wvA, (e2 << 2) | hd)
                             : __shfl(wvB, ((e2 - 16) << 2) | hd);
        float2 v = __half22float2(hv[e2]);
        accx = fmaf(av, v.x, accx);
        accy = fmaf(av, v.y, accy);
    }
}

// ---- layer-1 edge pass: one wave per node; 32-slot chunks + sized tail ----
__global__ void __launch_bounds__(256) edge1_kernel(
    const int* __restrict__ csr, const int* __restrict__ rowp,
    const __half2* __restrict__ h1, const float* __restrict__ as1,
    const float* __restrict__ ad1, const float* __restrict__ b1,
    __half* __restrict__ x2h, int N)
{
    int lane = threadIdx.x & 63;
    int n = __builtin_amdgcn_readfirstlane(blockIdx.x * 4 + (threadIdx.x >> 6));
    if (n >= N) return;
    int rs = rowp[n], re = rowp[n + 1];
    int hd = lane >> 4;
    int el = lane >> 2, hh = lane & 3;
    float adv = ad1[n * 4 + hh];
    float accx = 0.f, accy = 0.f, srun = 0.f;
    int base = rs, rem = re - rs;
    while (rem >= 32) {
        chunk1<32>(csr, base, 32, as1, adv, el, hh, hd, lane, h1, accx, accy, srun);
        base += 32; rem -= 32;
    }
    if (rem > 24)      chunk1<32>(csr, base, rem, as1, adv, el, hh, hd, lane, h1, accx, accy, srun);
    else if (rem > 16) chunk1<24>(csr, base, rem, as1, adv, el, hh, hd, lane, h1, accx, accy, srun);
    else if (rem > 8)  chunk1<16>(csr, base, rem, as1, adv, el, hh, hd, lane, h1, accx, accy, srun);
    else if (rem > 0)  chunk1<8> (csr, base, rem, as1, adv, el, hh, hd, lane, h1, accx, accy, srun);

    float sden = __shfl(srun, hd) + 1e-16f;
    float inv = 1.f / sden;
    float2 bv = *(const float2*)(b1 + lane * 2);
    float o0 = accx * inv + bv.x;
    float o1 = accy * inv + bv.y;
    o0 = o0 > 0.f ? o0 : (__expf(o0) - 1.f);   // ELU
    o1 = o1 > 0.f ? o1 : (__expf(o1) - 1.f);
    *(__half2*)(x2h + (size_t)n * 128 + lane * 2) = __floats2half2_rn(o0, o1);
}

// ---- edge2 chunk: K-slot staged gather (K <= 16) ----
template<int K>
__device__ __forceinline__ void chunk2(
    const int* __restrict__ csr, int base, int cnt,
    const float* __restrict__ as2, float adv, int lane,
    const __half* __restrict__ h2, float& acc, float& srun)
{
    float wv = 0.f;
    if (lane < cnt) {
        int s = csr[base + lane];
        float e = as2[s] + adv;
        e = e > 0.f ? e : LRELU_SLOPE * e;
        wv = __expf(e);
    }
    srun += wv;
    __half hv[K];
    #pragma unroll
    for (int e2 = 0; e2 < K; ++e2) {
        int ee = e2 < cnt ? e2 : cnt - 1;      // wave-uniform clamp
        int s = csr[base + ee];                // uniform -> s_load
        hv[e2] = h2[(size_t)s * 64 + lane];
    }
    #pragma unroll
    for (int e2 = 0; e2 < K; ++e2) {
        float av = __shfl(wv, e2);             // 0 for padded slots
        acc = fmaf(av, __half2float(hv[e2]), acc);
    }
}

// ---- layer-2 edge pass + fused node-MLP projection ----
// Aggregation: lane = channel (as before). Then the wave's 64-ch row is
// staged in LDS (wave-local) and each lane computes one u/v output:
// lane<32 -> u_j (j=lane), lane>=32 -> v_j. Weights loaded AFTER the gather
// loop to keep peak VGPR low.
__global__ void __launch_bounds__(256) edge2_mlp_kernel(
    const int* __restrict__ csr, const int* __restrict__ rowp,
    const __half* __restrict__ h2, const float* __restrict__ as2,
    const float* __restrict__ ad2, const float* __restrict__ b2,
    const float* __restrict__ Wm1T, __half* __restrict__ uv, int N)
{
    __shared__ float ols[4][64];
    int lane = threadIdx.x & 63;
    int wvid = threadIdx.x >> 6;
    int n = __builtin_amdgcn_readfirstlane(blockIdx.x * 4 + wvid);
    if (n >= N) return;
    int rs = rowp[n], re = rowp[n + 1];
    float adv = ad2[n];
    float acc = 0.f, srun = 0.f;
    int base = rs, rem = re - rs;
    while (rem >= 16) {
        chunk2<16>(csr, base, 16, as2, adv, lane, h2, acc, srun);
        base += 16; rem -= 16;
    }
    if (rem > 8)      chunk2<16>(csr, base, rem, as2, adv, lane, h2, acc, srun);
    else if (rem > 0) chunk2<8> (csr, base, rem, as2, adv, lane, h2, acc, srun);

    #pragma unroll
    for (int m = 1; m < 64; m <<= 1) srun += __shfl_xor(srun, m);
    float o = acc / (srun + 1e-16f) + b2[lane];
    ols[wvid][lane] = o;                       // wave-local; no barrier needed

    // projection: lane j computes uv[n][lane] = dot(row, Wm1T[j][half*64..])
    int j = lane & 31, half = lane >> 5;
    const float* wr = Wm1T + j * 128 + half * 64;
    float dot = 0.f;
    #pragma unroll
    for (int q = 0; q < 16; q++) {
        float4 wv4 = ((const float4*)wr)[q];
        float4 hv4 = *(const float4*)&ols[wvid][q * 4];   // broadcast read
        dot = fmaf(hv4.x, wv4.x, dot);
        dot = fmaf(hv4.y, wv4.y, dot);
        dot = fmaf(hv4.z, wv4.z, dot);
        dot = fmaf(hv4.w, wv4.w, dot);
    }
    uv[(size_t)n * 64 + lane] = __float2half_rn(dot);
}

// ---- pair MLP: 2 lanes per pair (16 hidden units each), shfl-reduce ----
__global__ void __launch_bounds__(256) pair_mlp_kernel(
    const int* __restrict__ ps, const int* __restrict__ pd,
    const __half2* __restrict__ uv, const float* __restrict__ bm1,
    const float* __restrict__ Wm2, const float* __restrict__ bm2,
    float* __restrict__ out, int P)
{
    int gid = blockIdx.x * 256 + threadIdx.x;
    int p = gid >> 1;
    if (p >= P) return;
    int half = gid & 1;
    int j0 = half * 8;
    int a = ps[p], b = pd[p];
    const __half2* ua = uv + (size_t)a * 32 + j0;
    const __half2* vb = uv + (size_t)b * 32 + 16 + j0;
    float r = 0.f;
    #pragma unroll
    for (int q = 0; q < 8; q++) {
        float2 uu = __half22float2(ua[q]);
        float2 vv = __half22float2(vb[q]);
        float2 bb = *(const float2*)(bm1 + half * 16 + q * 2);
        float2 ww = *(const float2*)(Wm2 + half * 16 + q * 2);
        float h0 = uu.x + vv.x + bb.x; h0 = h0 > 0.f ? h0 : 0.f; r = fmaf(h0, ww.x, r);
        float h1 = uu.y + vv.y + bb.y; h1 = h1 > 0.f ? h1 : 0.f; r = fmaf(h1, ww.y, r);
    }
    r += __shfl_xor(r, 1);
    if (half == 0) out[p] = r + bm2[0];
}

extern "C" void kernel_launch(void* const* d_in, const int* in_sizes, int n_in,
                              void* d_out, int out_size, void* d_ws, size_t ws_size,
                              hipStream_t stream)
{
    const float* x    = (const float*)d_in[0];
    const int*   ei   = (const int*)  d_in[1];
    const int*   ep   = (const int*)  d_in[2];
    const float* W1   = (const float*)d_in[3];
    const float* atS1 = (const float*)d_in[4];
    const float* atD1 = (const float*)d_in[5];
    const float* b1   = (const float*)d_in[6];
    const float* W2   = (const float*)d_in[7];
    const float* atS2 = (const float*)d_in[8];
    const float* atD2 = (const float*)d_in[9];
    const float* b2   = (const float*)d_in[10];
    const float* Wm1  = (const float*)d_in[11];
    const float* bm1  = (const float*)d_in[12];
    const float* Wm2  = (const float*)d_in[13];
    const float* bm2  = (const float*)d_in[14];
    float* out = (float*)d_out;

    int N = in_sizes[0] / 128;
    int E = in_sizes[1] / 2;
    int P = in_sizes[2] / 2;
    int Etot = E + N;
    int EN = Etot;
    int nbkt = (N + (1 << BKT_SH) - 1) >> BKT_SH;
    int nbA  = (EN + 4095) / 4096;

    // workspace carve (256B aligned)
    char* w = (char*)d_ws;
    auto alloc = [&](size_t bytes) {
        char* p = w; w += (bytes + 255) & ~(size_t)255; return p;
    };
    _Float16* W1Th = (_Float16*)alloc(16384 * 2);
    _Float16* W2Th = (_Float16*)alloc(8192 * 2);
    float*    Wm1T = (float*)alloc(4096 * 4);
    _Float16* h1   = (_Float16*)alloc((size_t)N * 128 * 2);  // fp16
    __half*   x2h  = (__half*)alloc((size_t)N * 128 * 2);    // fp16
    _Float16* h2   = (_Float16*)alloc((size_t)N * 64 * 2);   // fp16
    int*      rowp = (int*)alloc((size_t)(N + 1) * 4);
    int*      bktoff = (int*)alloc((size_t)(nbkt + 1) * 4);
    int*      csrs = (int*)alloc((size_t)Etot * 4);
    uint2*    ebuf = (uint2*)alloc((size_t)Etot * 8);
    int*      lcnt_g = (int*)alloc((size_t)nbA * nbkt * 4);
    float*    as1  = (float*)alloc((size_t)N * 4 * 4);
    float*    ad1  = (float*)alloc((size_t)N * 4 * 4);
    float*    as2  = (float*)alloc((size_t)N * 4);
    float*    ad2  = (float*)alloc((size_t)N * 4);
    __half*   uv   = (__half*)alloc((size_t)N * 64 * 2);

    prep_kernel<<<112, 256, 0, stream>>>(W1, W2, Wm1, W1Th, W2Th, Wm1T);

    int nbG = (N + 63) / 64;
    gemm1_passA_kernel<<<2 * nbG + nbA, 256, 0, stream>>>(
        x, W1Th, atS1, atD1, h1, as1, ad1, N, nbG,
        ei, ei + E, E, lcnt_g, nbkt);

    scanb2_kernel<<<1, 512, 0, stream>>>(lcnt_g, bktoff, nbkt, nbA);
    passB_kernel<<<nbA, 256, 0, stream>>>(ei, ei + E, E, N, bktoff, lcnt_g,
                                          ebuf, nbkt);
    build_kernel<<<nbkt, 256, 0, stream>>>(ebuf, bktoff, rowp, csrs, N, nbkt);

    edge1_kernel<<<(N + 3) / 4, 256, 0, stream>>>(csrs, rowp, (const __half2*)h1,
                                                  as1, ad1, b1, x2h, N);
    gemm2_kernel<<<nbG, 256, 0, stream>>>((const _Float16*)x2h, W2Th, atS2, atD2,
                                          h2, as2, ad2, N);
    edge2_mlp_kernel<<<(N + 3) / 4, 256, 0, stream>>>(csrs, rowp,
                                                      (const __half*)h2,
                                                      as2, ad2, b2, Wm1T, uv, N);

    pair_mlp_kernel<<<(2 * P + 255) / 256, 256, 0, stream>>>(ep, ep + P,
                                                             (const __half2*)uv,
                                                             bm1, Wm2, bm2, out, P);
}

// Round 16
// 215.394 us; speedup vs baseline: 1.2132x; 1.2132x over previous
//
#include <hip/hip_runtime.h>
#include <hip/hip_bf16.h>
#include <hip/hip_fp16.h>

// ---------------------------------------------------------------------------
// GAT link predictor: 2x GATConv + pair MLP.
// R16: revert R15's edge2+node_mlp fusion (latency pathology, suspected
//      scratch spill); keep zero-free CSR build (passA raw counts, scanb2,
//      passB, build). Separate edge2 (fp32 hf) + node_mlp as in R14.
//      MFMA f16 GEMMs, fp16 gather tables, 32-slot+tail edge1. 10 launches.
// ---------------------------------------------------------------------------

#define LRELU_SLOPE 0.2f
#define BKT_SH 7
#define NB_MAX 512

typedef _Float16 v8h __attribute__((ext_vector_type(8)));
typedef float    v4f __attribute__((ext_vector_type(4)));

// ---- weight prep (no zeroing needed anywhere) ----
__global__ void __launch_bounds__(256) prep_kernel(
    const float* __restrict__ W1, const float* __restrict__ W2,
    const float* __restrict__ Wm1,
    _Float16* __restrict__ W1Th, _Float16* __restrict__ W2Th,
    float* __restrict__ Wm1T)
{
    int i = blockIdx.x * 256 + threadIdx.x;
    if (i < 16384) {                       // W1 [128][128] -> W1Th [128][128]
        int k = i >> 7, j = i & 127;
        W1Th[j * 128 + k] = (_Float16)W1[i];
    } else if (i < 16384 + 8192) {         // W2 [128][64] -> W2Th [64][128]
        int t = i - 16384;
        int k = t >> 6, j = t & 63;
        W2Th[j * 128 + k] = (_Float16)W2[t];
    } else if (i < 16384 + 8192 + 4096) {  // Wm1 [128][32] -> Wm1T [32][128]
        int t = i - 24576;
        int k = t >> 5, j = t & 31;
        Wm1T[j * 128 + k] = Wm1[t];
    }
}

// ---- MFMA f16 GEMM + fused attention scores (device body) ----
template<int AHALF>
__device__ __forceinline__ void gemm_att_body(
    int bx, int by,
    const void* __restrict__ Xv, const _Float16* __restrict__ WTH,
    const float* __restrict__ atts, const float* __restrict__ attd,
    _Float16* __restrict__ OUT, float* __restrict__ oas, float* __restrict__ oad,
    int N, int ncols, int H, int headShift)
{
    __shared__ _Float16 cs[64 * 68];
    int tid = threadIdx.x;
    int lane = tid & 63;
    int wv = tid >> 6;
    int rowBase = bx * 64 + wv * 16;
    int colBase = by * 64;
    int lr = lane & 15;
    int lk = lane >> 4;

    v8h bf[4][4];
    #pragma unroll
    for (int ct = 0; ct < 4; ct++) {
        const _Float16* bp = WTH + (size_t)(colBase + ct * 16 + lr) * 128 + lk * 8;
        #pragma unroll
        for (int ks = 0; ks < 4; ks++)
            bf[ct][ks] = *(const v8h*)(bp + ks * 32);
    }

    int arow = rowBase + lr;
    if (arow >= N) arow = N - 1;            // clamp; stores masked below
    v4f acc[4];
    #pragma unroll
    for (int ct = 0; ct < 4; ct++) acc[ct] = (v4f){0.f, 0.f, 0.f, 0.f};

    if (AHALF) {
        const _Float16* ap = (const _Float16*)Xv + (size_t)arow * 128 + lk * 8;
        #pragma unroll
        for (int ks = 0; ks < 4; ks++) {
            v8h af = *(const v8h*)(ap + ks * 32);
            #pragma unroll
            for (int ct = 0; ct < 4; ct++)
                acc[ct] = __builtin_amdgcn_mfma_f32_16x16x32_f16(af, bf[ct][ks],
                                                                 acc[ct], 0, 0, 0);
        }
    } else {
        const float* ap = (const float*)Xv + (size_t)arow * 128 + lk * 8;
        #pragma unroll
        for (int ks = 0; ks < 4; ks++) {
            float4 a0 = *(const float4*)(ap + ks * 32);
            float4 a1 = *(const float4*)(ap + ks * 32 + 4);
            v8h af;
            af[0] = (_Float16)a0.x; af[1] = (_Float16)a0.y;
            af[2] = (_Float16)a0.z; af[3] = (_Float16)a0.w;
            af[4] = (_Float16)a1.x; af[5] = (_Float16)a1.y;
            af[6] = (_Float16)a1.z; af[7] = (_Float16)a1.w;
            #pragma unroll
            for (int ct = 0; ct < 4; ct++)
                acc[ct] = __builtin_amdgcn_mfma_f32_16x16x32_f16(af, bf[ct][ks],
                                                                 acc[ct], 0, 0, 0);
        }
    }

    int ctPerHead = (1 << headShift) >> 4;        // 2 (L1) or 4 (L2)
    #pragma unroll
    for (int hh = 0; hh < 2; hh++) {
        if (hh * ctPerHead >= 4) break;
        float ps[4] = {0.f, 0.f, 0.f, 0.f};
        float pd[4] = {0.f, 0.f, 0.f, 0.f};
        for (int c2 = 0; c2 < ctPerHead; c2++) {
            int ct = hh * ctPerHead + c2;
            int col = colBase + ct * 16 + lr;
            float ws = atts[col], wd = attd[col];
            #pragma unroll
            for (int r = 0; r < 4; r++) {
                ps[r] = fmaf(acc[ct][r], ws, ps[r]);
                pd[r] = fmaf(acc[ct][r], wd, pd[r]);
            }
        }
        #pragma unroll
        for (int r = 0; r < 4; r++) {
            #pragma unroll
            for (int m = 1; m < 16; m <<= 1) {
                ps[r] += __shfl_xor(ps[r], m);
                pd[r] += __shfl_xor(pd[r], m);
            }
        }
        if (lr == 0) {
            int head = (colBase >> headShift) + hh;
            #pragma unroll
            for (int r = 0; r < 4; r++) {
                int row = rowBase + lk * 4 + r;
                if (row < N) {
                    oas[(size_t)row * H + head] = ps[r];
                    oad[(size_t)row * H + head] = pd[r];
                }
            }
        }
    }

    #pragma unroll
    for (int ct = 0; ct < 4; ct++)
        #pragma unroll
        for (int r = 0; r < 4; r++)
            cs[(wv * 16 + lk * 4 + r) * 68 + ct * 16 + lr] = (_Float16)acc[ct][r];
    __syncthreads();
    int rr = tid >> 2;
    int cb = (tid & 3) * 16;
    int grow = bx * 64 + rr;
    if (grow < N) {
        const uint4* sp = (const uint4*)(cs + rr * 68 + cb);
        _Float16* op = OUT + (size_t)grow * ncols + colBase + cb;
        uint4 w0 = sp[0];
        uint4 w1 = sp[1];
        *(uint4*)op = w0;
        *(uint4*)(op + 8) = w1;
    }
}

// ---- passA body: LDS bucket histogram -> raw per-(block,bucket) counts ----
__device__ __forceinline__ void passA_body(
    int blk, const int* __restrict__ src, const int* __restrict__ dst,
    int E, int N, int* __restrict__ lcnt_g, int nbkt)
{
    __shared__ int lcnt[NB_MAX];
    int tid = threadIdx.x;
    int EN = E + N;
    int base = blk * 4096;
    for (int b = tid; b < nbkt; b += 256) lcnt[b] = 0;
    __syncthreads();
    #pragma unroll
    for (int j = 0; j < 16; j++) {
        int i = base + j * 256 + tid;
        if (i < EN) {
            int d = (i < E) ? dst[i] : (i - E);
            atomicAdd(&lcnt[d >> BKT_SH], 1);
        }
    }
    __syncthreads();
    for (int b = tid; b < nbkt; b += 256)
        lcnt_g[(size_t)blk * nbkt + b] = lcnt[b];
}

// ---- fused: gemm1 (blocks [0, 2*nbG)) || passA (rest) ----
__global__ void __launch_bounds__(256) gemm1_passA_kernel(
    const float* __restrict__ X, const _Float16* __restrict__ WTH,
    const float* __restrict__ atts, const float* __restrict__ attd,
    _Float16* __restrict__ OUT, float* __restrict__ oas, float* __restrict__ oad,
    int N, int nbG,
    const int* __restrict__ src, const int* __restrict__ dst, int E,
    int* __restrict__ lcnt_g, int nbkt)
{
    if ((int)blockIdx.x < 2 * nbG) {
        gemm_att_body<0>(blockIdx.x % nbG, blockIdx.x / nbG, X, WTH, atts, attd,
                         OUT, oas, oad, N, 128, 4, 5);
    } else {
        passA_body((int)blockIdx.x - 2 * nbG, src, dst, E, N, lcnt_g, nbkt);
    }
}

__global__ void __launch_bounds__(256) gemm2_kernel(
    const _Float16* __restrict__ X, const _Float16* __restrict__ WTH,
    const float* __restrict__ atts, const float* __restrict__ attd,
    _Float16* __restrict__ OUT, float* __restrict__ oas, float* __restrict__ oad,
    int N)
{
    gemm_att_body<1>(blockIdx.x, 0, X, WTH, atts, attd, OUT, oas, oad,
                     N, 64, 1, 6);
}

// ---- scanb2: per-bucket block-prefix in place + bucket scan -> bktoff ----
__global__ void __launch_bounds__(512) scanb2_kernel(
    int* __restrict__ lcnt_g, int* __restrict__ bktoff, int nbkt, int nbA)
{
    __shared__ int wsum[8];
    int t = threadIdx.x;
    int cum = 0;
    if (t < nbkt) {
        for (int blk = 0; blk < nbA; ++blk) {
            size_t idx = (size_t)blk * nbkt + t;
            int v = lcnt_g[idx];
            lcnt_g[idx] = cum;          // exclusive block-prefix for bucket t
            cum += v;
        }
    }
    int lane = t & 63, wid = t >> 6;
    int v = (t < nbkt) ? cum : 0;
    #pragma unroll
    for (int off = 1; off < 64; off <<= 1) {
        int y = __shfl_up(v, off);
        if (lane >= off) v += y;
    }
    if (lane == 63) wsum[wid] = v;
    __syncthreads();
    if (wid == 0) {
        int s = (lane < 8) ? wsum[lane] : 0;
        #pragma unroll
        for (int off = 1; off < 8; off <<= 1) {
            int y = __shfl_up(s, off);
            if (lane >= off) s += y;
        }
        if (lane < 8) wsum[lane] = s;
    }
    __syncthreads();
    if (wid > 0) v += wsum[wid - 1];
    if (t < nbkt) bktoff[t + 1] = v;
    if (t == 0) bktoff[0] = 0;
}

// ---- passB: write bucket-major (d,s) runs via LDS cursors ----
__global__ void __launch_bounds__(256) passB_kernel(
    const int* __restrict__ src, const int* __restrict__ dst, int E, int N,
    const int* __restrict__ bktoff, const int* __restrict__ lcnt_g,
    uint2* __restrict__ ebuf, int nbkt)
{
    __shared__ int sbase[NB_MAX];
    __shared__ int loff[NB_MAX];
    int blk = blockIdx.x;
    int tid = threadIdx.x;
    int EN = E + N;
    int base = blk * 4096;
    for (int b = tid; b < nbkt; b += 256) {
        sbase[b] = bktoff[b] + lcnt_g[(size_t)blk * nbkt + b];
        loff[b] = 0;
    }
    __syncthreads();
    #pragma unroll
    for (int j = 0; j < 16; j++) {
        int i = base + j * 256 + tid;
        if (i < EN) {
            int s, d;
            if (i < E) { s = src[i]; d = dst[i]; } else { s = d = i - E; }
            int b = d >> BKT_SH;
            int off = atomicAdd(&loff[b], 1);
            ebuf[(size_t)sbase[b] + off] = make_uint2((unsigned)d, (unsigned)s);
        }
    }
}

// ---- build: per-bucket node hist + in-block scan -> rowp + csrs ----
__global__ void __launch_bounds__(256) build_kernel(
    const uint2* __restrict__ ebuf, const int* __restrict__ bktoff,
    int* __restrict__ rowp, int* __restrict__ csrs, int N, int nbkt)
{
    __shared__ int ldeg[128];
    __shared__ int lrow[129];
    __shared__ int lcur[128];
    __shared__ int w0tot;
    int b = blockIdx.x;
    if (b >= nbkt) return;
    int n0 = b << BKT_SH;
    int n1 = n0 + 128; if (n1 > N) n1 = N;
    int r0 = bktoff[b], r1 = bktoff[b + 1];
    int t = threadIdx.x;
    if (t < 128) { ldeg[t] = 0; lcur[t] = 0; }
    __syncthreads();
    for (int i = r0 + t; i < r1; i += 256)
        atomicAdd(&ldeg[(int)ebuf[i].x - n0], 1);
    __syncthreads();
    int lane = t & 63;
    int v = (t < 128) ? ldeg[t] : 0;
    #pragma unroll
    for (int off = 1; off < 64; off <<= 1) {
        int y = __shfl_up(v, off);
        if (lane >= off) v += y;
    }
    if (t == 63) w0tot = v;
    __syncthreads();
    if (t >= 64 && t < 128) v += w0tot;
    if (t < 128) lrow[t + 1] = v;
    if (t == 0) { lrow[0] = 0; rowp[n0] = r0; }
    if (t < n1 - n0) rowp[n0 + t + 1] = r0 + v;
    __syncthreads();
    for (int i = r0 + t; i < r1; i += 256) {
        uint2 e = ebuf[i];
        int d = (int)e.x - n0;
        int pos = r0 + lrow[d] + atomicAdd(&lcur[d], 1);
        csrs[pos] = (int)e.y;
    }
}

// ---- edge1 chunk: K-slot staged gather + FMA (padding clamps/zeros) ----
template<int K>
__device__ __forceinline__ void chunk1(
    const int* __restrict__ csr, int base, int cnt,
    const float* __restrict__ as1, float adv,
    int el, int hh, int hd, int lane, const __half2* __restrict__ h1,
    float& accx, float& accy, float& srun)
{
    float wvA = 0.f, wvB = 0.f;
    if (el < cnt) {
        int s = csr[base + el];
        float e = as1[s * 4 + hh] + adv;
        e = e > 0.f ? e : LRELU_SLOPE * e;
        wvA = __expf(e);
    }
    if (K > 16 && el + 16 < cnt) {
        int s = csr[base + 16 + el];
        float e = as1[s * 4 + hh] + adv;
        e = e > 0.f ? e : LRELU_SLOPE * e;
        wvB = __expf(e);
    }
    float t = wvA + wvB;
    t += __shfl_xor(t, 4);  t += __shfl_xor(t, 8);
    t += __shfl_xor(t, 16); t += __shfl_xor(t, 32);
    srun += t;
    __half2 hv[K];
    #pragma unroll
    for (int e2 = 0; e2 < K; ++e2) {
        int ee = e2 < cnt ? e2 : cnt - 1;      // wave-uniform clamp
        int s = csr[base + ee];                // uniform -> s_load
        hv[e2] = h1[(size_t)s * 64 + lane];
    }
    #pragma unroll
    for (int e2 = 0; e2 < K; ++e2) {
        float av = (e2 < 16) ? __shfl(wvA, (e2 << 2) | hd)
                             : __shfl(wvB, ((e2 - 16) << 2) | hd);
        float2 v = __half22float2(hv[e2]);
        accx = fmaf(av, v.x, accx);
        accy = fmaf(av, v.y, accy);
    }
}

// ---- layer-1 edge pass: one wave per node; 32-slot chunks + sized tail ----
__global__ void __launch_bounds__(256) edge1_kernel(
    const int* __restrict__ csr, const int* __restrict__ rowp,
    const __half2* __restrict__ h1, const float* __restrict__ as1,
    const float* __restrict__ ad1, const float* __restrict__ b1,
    __half* __restrict__ x2h, int N)
{
    int lane = threadIdx.x & 63;
    int n = __builtin_amdgcn_readfirstlane(blockIdx.x * 4 + (threadIdx.x >> 6));
    if (n >= N) return;
    int rs = rowp[n], re = rowp[n + 1];
    int hd = lane >> 4;
    int el = lane >> 2, hh = lane & 3;
    float adv = ad1[n * 4 + hh];
    float accx = 0.f, accy = 0.f, srun = 0.f;
    int base = rs, rem = re - rs;
    while (rem >= 32) {
        chunk1<32>(csr, base, 32, as1, adv, el, hh, hd, lane, h1, accx, accy, srun);
        base += 32; rem -= 32;
    }
    if (rem > 24)      chunk1<32>(csr, base, rem, as1, adv, el, hh, hd, lane, h1, accx, accy, srun);
    else if (rem > 16) chunk1<24>(csr, base, rem, as1, adv, el, hh, hd, lane, h1, accx, accy, srun);
    else if (rem > 8)  chunk1<16>(csr, base, rem, as1, adv, el, hh, hd, lane, h1, accx, accy, srun);
    else if (rem > 0)  chunk1<8> (csr, base, rem, as1, adv, el, hh, hd, lane, h1, accx, accy, srun);

    float sden = __shfl(srun, hd) + 1e-16f;
    float inv = 1.f / sden;
    float2 bv = *(const float2*)(b1 + lane * 2);
    float o0 = accx * inv + bv.x;
    float o1 = accy * inv + bv.y;
    o0 = o0 > 0.f ? o0 : (__expf(o0) - 1.f);   // ELU
    o1 = o1 > 0.f ? o1 : (__expf(o1) - 1.f);
    *(__half2*)(x2h + (size_t)n * 128 + lane * 2) = __floats2half2_rn(o0, o1);
}

// ---- edge2 chunk: K-slot staged gather (K <= 16) ----
template<int K>
__device__ __forceinline__ void chunk2(
    const int* __restrict__ csr, int base, int cnt,
    const float* __restrict__ as2, float adv, int lane,
    const __half* __restrict__ h2, float& acc, float& srun)
{
    float wv = 0.f;
    if (lane < cnt) {
        int s = csr[base + lane];
        float e = as2[s] + adv;
        e = e > 0.f ? e : LRELU_SLOPE * e;
        wv = __expf(e);
    }
    srun += wv;
    __half hv[K];
    #pragma unroll
    for (int e2 = 0; e2 < K; ++e2) {
        int ee = e2 < cnt ? e2 : cnt - 1;      // wave-uniform clamp
        int s = csr[base + ee];                // uniform -> s_load
        hv[e2] = h2[(size_t)s * 64 + lane];
    }
    #pragma unroll
    for (int e2 = 0; e2 < K; ++e2) {
        float av = __shfl(wv, e2);             // 0 for padded slots
        acc = fmaf(av, __half2float(hv[e2]), acc);
    }
}

// ---- layer-2 edge pass (1 head, 64 channels; lane = channel) ----
__global__ void __launch_bounds__(256) edge2_kernel(
    const int* __restrict__ csr, const int* __restrict__ rowp,
    const __half* __restrict__ h2, const float* __restrict__ as2,
    const float* __restrict__ ad2, const float* __restrict__ b2,
    float* __restrict__ hf, int N)
{
    int lane = threadIdx.x & 63;
    int n = __builtin_amdgcn_readfirstlane(blockIdx.x * 4 + (threadIdx.x >> 6));
    if (n >= N) return;
    int rs = rowp[n], re = rowp[n + 1];
    float adv = ad2[n];
    float acc = 0.f, srun = 0.f;
    int base = rs, rem = re - rs;
    while (rem >= 16) {
        chunk2<16>(csr, base, 16, as2, adv, lane, h2, acc, srun);
        base += 16; rem -= 16;
    }
    if (rem > 8)      chunk2<16>(csr, base, rem, as2, adv, lane, h2, acc, srun);
    else if (rem > 0) chunk2<8> (csr, base, rem, as2, adv, lane, h2, acc, srun);

    #pragma unroll
    for (int m = 1; m < 64; m <<= 1) srun += __shfl_xor(srun, m);
    float o = acc / (srun + 1e-16f) + b2[lane];
    hf[(size_t)n * 64 + lane] = o;
}

// ---- per-node MLP projections: u|v = hf[n] @ Wm1 halves; uv fp16 ----
__global__ void __launch_bounds__(256) node_mlp_kernel(
    const float* __restrict__ hf, const float* __restrict__ Wm1T,
    __half* __restrict__ uv, int N)
{
    int lane = threadIdx.x & 63;
    int j = lane & 31, half = lane >> 5;
    const float* wr = Wm1T + j * 128 + half * 64;
    float wreg[64];
    #pragma unroll
    for (int q = 0; q < 16; q++) {
        float4 t = ((const float4*)wr)[q];
        wreg[q*4] = t.x; wreg[q*4+1] = t.y; wreg[q*4+2] = t.z; wreg[q*4+3] = t.w;
    }
    int wgid = __builtin_amdgcn_readfirstlane(blockIdx.x * 4 + (threadIdx.x >> 6));
    int nwaves = gridDim.x * 4;
    for (int n = wgid; n < N; n += nwaves) {
        const float* hr = hf + (size_t)n * 64;
        float acc = 0.f;
        #pragma unroll
        for (int k = 0; k < 64; k += 4) {
            float4 hv = *(const float4*)(hr + k);   // uniform across wave
            acc = fmaf(hv.x, wreg[k],   acc);
            acc = fmaf(hv.y, wreg[k+1], acc);
            acc = fmaf(hv.z, wreg[k+2], acc);
            acc = fmaf(hv.w, wreg[k+3], acc);
        }
        uv[(size_t)n * 64 + lane] = __float2half_rn(acc);
    }
}

// ---- pair MLP: 2 lanes per pair (16 hidden units each), shfl-reduce ----
__global__ void __launch_bounds__(256) pair_mlp_kernel(
    const int* __restrict__ ps, const int* __restrict__ pd,
    const __half2* __restrict__ uv, const float* __restrict__ bm1,
    const float* __restrict__ Wm2, const float* __restrict__ bm2,
    float* __restrict__ out, int P)
{
    int gid = blockIdx.x * 256 + threadIdx.x;
    int p = gid >> 1;
    if (p >= P) return;
    int half = gid & 1;
    int j0 = half * 8;
    int a = ps[p], b = pd[p];
    const __half2* ua = uv + (size_t)a * 32 + j0;
    const __half2* vb = uv + (size_t)b * 32 + 16 + j0;
    float r = 0.f;
    #pragma unroll
    for (int q = 0; q < 8; q++) {
        float2 uu = __half22float2(ua[q]);
        float2 vv = __half22float2(vb[q]);
        float2 bb = *(const float2*)(bm1 + half * 16 + q * 2);
        float2 ww = *(const float2*)(Wm2 + half * 16 + q * 2);
        float h0 = uu.x + vv.x + bb.x; h0 = h0 > 0.f ? h0 : 0.f; r = fmaf(h0, ww.x, r);
        float h1 = uu.y + vv.y + bb.y; h1 = h1 > 0.f ? h1 : 0.f; r = fmaf(h1, ww.y, r);
    }
    r += __shfl_xor(r, 1);
    if (half == 0) out[p] = r + bm2[0];
}

extern "C" void kernel_launch(void* const* d_in, const int* in_sizes, int n_in,
                              void* d_out, int out_size, void* d_ws, size_t ws_size,
                              hipStream_t stream)
{
    const float* x    = (const float*)d_in[0];
    const int*   ei   = (const int*)  d_in[1];
    const int*   ep   = (const int*)  d_in[2];
    const float* W1   = (const float*)d_in[3];
    const float* atS1 = (const float*)d_in[4];
    const float* atD1 = (const float*)d_in[5];
    const float* b1   = (const float*)d_in[6];
    const float* W2   = (const float*)d_in[7];
    const float* atS2 = (const float*)d_in[8];
    const float* atD2 = (const float*)d_in[9];
    const float* b2   = (const float*)d_in[10];
    const float* Wm1  = (const float*)d_in[11];
    const float* bm1  = (const float*)d_in[12];
    const float* Wm2  = (const float*)d_in[13];
    const float* bm2  = (const float*)d_in[14];
    float* out = (float*)d_out;

    int N = in_sizes[0] / 128;
    int E = in_sizes[1] / 2;
    int P = in_sizes[2] / 2;
    int Etot = E + N;
    int EN = Etot;
    int nbkt = (N + (1 << BKT_SH) - 1) >> BKT_SH;
    int nbA  = (EN + 4095) / 4096;

    // workspace carve (256B aligned)
    char* w = (char*)d_ws;
    auto alloc = [&](size_t bytes) {
        char* p = w; w += (bytes + 255) & ~(size_t)255; return p;
    };
    _Float16* W1Th = (_Float16*)alloc(16384 * 2);
    _Float16* W2Th = (_Float16*)alloc(8192 * 2);
    float*    Wm1T = (float*)alloc(4096 * 4);
    _Float16* h1   = (_Float16*)alloc((size_t)N * 128 * 2);  // fp16
    __half*   x2h  = (__half*)alloc((size_t)N * 128 * 2);    // fp16
    _Float16* h2   = (_Float16*)alloc((size_t)N * 64 * 2);   // fp16
    float*    hf   = (float*)alloc((size_t)N * 64 * 4);
    int*      rowp = (int*)alloc((size_t)(N + 1) * 4);
    int*      bktoff = (int*)alloc((size_t)(nbkt + 1) * 4);
    int*      csrs = (int*)alloc((size_t)Etot * 4);
    uint2*    ebuf = (uint2*)alloc((size_t)Etot * 8);
    int*      lcnt_g = (int*)alloc((size_t)nbA * nbkt * 4);
    float*    as1  = (float*)alloc((size_t)N * 4 * 4);
    float*    ad1  = (float*)alloc((size_t)N * 4 * 4);
    float*    as2  = (float*)alloc((size_t)N * 4);
    float*    ad2  = (float*)alloc((size_t)N * 4);
    __half*   uv   = (__half*)alloc((size_t)N * 64 * 2);

    prep_kernel<<<112, 256, 0, stream>>>(W1, W2, Wm1, W1Th, W2Th, Wm1T);

    int nbG = (N + 63) / 64;
    gemm1_passA_kernel<<<2 * nbG + nbA, 256, 0, stream>>>(
        x, W1Th, atS1, atD1, h1, as1, ad1, N, nbG,
        ei, ei + E, E, lcnt_g, nbkt);

    scanb2_kernel<<<1, 512, 0, stream>>>(lcnt_g, bktoff, nbkt, nbA);
    passB_kernel<<<nbA, 256, 0, stream>>>(ei, ei + E, E, N, bktoff, lcnt_g,
                                          ebuf, nbkt);
    build_kernel<<<nbkt, 256, 0, stream>>>(ebuf, bktoff, rowp, csrs, N, nbkt);

    edge1_kernel<<<(N + 3) / 4, 256, 0, stream>>>(csrs, rowp, (const __half2*)h1,
                                                  as1, ad1, b1, x2h, N);
    gemm2_kernel<<<nbG, 256, 0, stream>>>((const _Float16*)x2h, W2Th, atS2, atD2,
                                          h2, as2, ad2, N);
    edge2_kernel<<<(N + 3) / 4, 256, 0, stream>>>(csrs, rowp, (const __half*)h2,
                                                  as2, ad2, b2, hf, N);

    node_mlp_kernel<<<1024, 256, 0, stream>>>(hf, Wm1T, uv, N);
    pair_mlp_kernel<<<(2 * P + 255) / 256, 256, 0, stream>>>(ep, ep + P,
                                                             (const __half2*)uv,
                                                             bm1, Wm2, bm2, out, P);
}

// Round 17
// 169.256 us; speedup vs baseline: 1.5439x; 1.2726x over previous
//
#include <hip/hip_runtime.h>
#include <hip/hip_bf16.h>
#include <hip/hip_fp16.h>

// ---------------------------------------------------------------------------
// GAT link predictor: 2x GATConv + pair MLP.
// R17: restore R14 verbatim (measured 169.3us): atomic-reservation passA +
//      tiny scanb + passB + build; separate edge2 + node_mlp; zero_prep
//      zeroes only bktcnt. R15's scanb2 (51us single-block serial scan) and
//      edge2 fusion are both reverted. MFMA f16 GEMMs, fp16 gather tables,
//      32-slot+tail edge1, factorized MLP. 10 launches.
// ---------------------------------------------------------------------------

#define LRELU_SLOPE 0.2f
#define BKT_SH 7
#define NB_MAX 512

typedef _Float16 v8h __attribute__((ext_vector_type(8)));
typedef float    v4f __attribute__((ext_vector_type(4)));

// ---- fused zero (bktcnt block) + weight prep ----
__global__ void __launch_bounds__(256) zero_prep_kernel(
    const float* __restrict__ W1, const float* __restrict__ W2,
    const float* __restrict__ Wm1,
    _Float16* __restrict__ W1Th, _Float16* __restrict__ W2Th,
    float* __restrict__ Wm1T, uint4* __restrict__ zp, int zn4)
{
    int i = blockIdx.x * 256 + threadIdx.x;
    if (i < zn4) zp[i] = make_uint4(0u, 0u, 0u, 0u);
    if (i < 16384) {                       // W1 [128][128] -> W1Th [128][128]
        int k = i >> 7, j = i & 127;
        W1Th[j * 128 + k] = (_Float16)W1[i];
    } else if (i < 16384 + 8192) {         // W2 [128][64] -> W2Th [64][128]
        int t = i - 16384;
        int k = t >> 6, j = t & 63;
        W2Th[j * 128 + k] = (_Float16)W2[t];
    } else if (i < 16384 + 8192 + 4096) {  // Wm1 [128][32] -> Wm1T [32][128]
        int t = i - 24576;
        int k = t >> 5, j = t & 31;
        Wm1T[j * 128 + k] = Wm1[t];
    }
}

// ---- MFMA f16 GEMM + fused attention scores (device body) ----
// Wave = 16 rows x 64 cols. A frag: row=lane&15, k=(lane>>4)*8+j.
// B frag: col=lane&15, same k. C/D: col=lane&15, row=(lane>>4)*4+reg.
template<int AHALF>
__device__ __forceinline__ void gemm_att_body(
    int bx, int by,
    const void* __restrict__ Xv, const _Float16* __restrict__ WTH,
    const float* __restrict__ atts, const float* __restrict__ attd,
    _Float16* __restrict__ OUT, float* __restrict__ oas, float* __restrict__ oad,
    int N, int ncols, int H, int headShift)
{
    __shared__ _Float16 cs[64 * 68];
    int tid = threadIdx.x;
    int lane = tid & 63;
    int wv = tid >> 6;
    int rowBase = bx * 64 + wv * 16;
    int colBase = by * 64;
    int lr = lane & 15;
    int lk = lane >> 4;

    v8h bf[4][4];
    #pragma unroll
    for (int ct = 0; ct < 4; ct++) {
        const _Float16* bp = WTH + (size_t)(colBase + ct * 16 + lr) * 128 + lk * 8;
        #pragma unroll
        for (int ks = 0; ks < 4; ks++)
            bf[ct][ks] = *(const v8h*)(bp + ks * 32);
    }

    int arow = rowBase + lr;
    if (arow >= N) arow = N - 1;            // clamp; stores masked below
    v4f acc[4];
    #pragma unroll
    for (int ct = 0; ct < 4; ct++) acc[ct] = (v4f){0.f, 0.f, 0.f, 0.f};

    if (AHALF) {
        const _Float16* ap = (const _Float16*)Xv + (size_t)arow * 128 + lk * 8;
        #pragma unroll
        for (int ks = 0; ks < 4; ks++) {
            v8h af = *(const v8h*)(ap + ks * 32);
            #pragma unroll
            for (int ct = 0; ct < 4; ct++)
                acc[ct] = __builtin_amdgcn_mfma_f32_16x16x32_f16(af, bf[ct][ks],
                                                                 acc[ct], 0, 0, 0);
        }
    } else {
        const float* ap = (const float*)Xv + (size_t)arow * 128 + lk * 8;
        #pragma unroll
        for (int ks = 0; ks < 4; ks++) {
            float4 a0 = *(const float4*)(ap + ks * 32);
            float4 a1 = *(const float4*)(ap + ks * 32 + 4);
            v8h af;
            af[0] = (_Float16)a0.x; af[1] = (_Float16)a0.y;
            af[2] = (_Float16)a0.z; af[3] = (_Float16)a0.w;
            af[4] = (_Float16)a1.x; af[5] = (_Float16)a1.y;
            af[6] = (_Float16)a1.z; af[7] = (_Float16)a1.w;
            #pragma unroll
            for (int ct = 0; ct < 4; ct++)
                acc[ct] = __builtin_amdgcn_mfma_f32_16x16x32_f16(af, bf[ct][ks],
                                                                 acc[ct], 0, 0, 0);
        }
    }

    int ctPerHead = (1 << headShift) >> 4;        // 2 (L1) or 4 (L2)
    #pragma unroll
    for (int hh = 0; hh < 2; hh++) {
        if (hh * ctPerHead >= 4) break;
        float ps[4] = {0.f, 0.f, 0.f, 0.f};
        float pd[4] = {0.f, 0.f, 0.f, 0.f};
        for (int c2 = 0; c2 < ctPerHead; c2++) {
            int ct = hh * ctPerHead + c2;
            int col = colBase + ct * 16 + lr;
            float ws = atts[col], wd = attd[col];
            #pragma unroll
            for (int r = 0; r < 4; r++) {
                ps[r] = fmaf(acc[ct][r], ws, ps[r]);
                pd[r] = fmaf(acc[ct][r], wd, pd[r]);
            }
        }
        #pragma unroll
        for (int r = 0; r < 4; r++) {
            #pragma unroll
            for (int m = 1; m < 16; m <<= 1) {
                ps[r] += __shfl_xor(ps[r], m);
                pd[r] += __shfl_xor(pd[r], m);
            }
        }
        if (lr == 0) {
            int head = (colBase >> headShift) + hh;
            #pragma unroll
            for (int r = 0; r < 4; r++) {
                int row = rowBase + lk * 4 + r;
                if (row < N) {
                    oas[(size_t)row * H + head] = ps[r];
                    oad[(size_t)row * H + head] = pd[r];
                }
            }
        }
    }

    #pragma unroll
    for (int ct = 0; ct < 4; ct++)
        #pragma unroll
        for (int r = 0; r < 4; r++)
            cs[(wv * 16 + lk * 4 + r) * 68 + ct * 16 + lr] = (_Float16)acc[ct][r];
    __syncthreads();
    int rr = tid >> 2;
    int cb = (tid & 3) * 16;
    int grow = bx * 64 + rr;
    if (grow < N) {
        const uint4* sp = (const uint4*)(cs + rr * 68 + cb);
        _Float16* op = OUT + (size_t)grow * ncols + colBase + cb;
        uint4 w0 = sp[0];
        uint4 w1 = sp[1];
        *(uint4*)op = w0;
        *(uint4*)(op + 8) = w1;
    }
}

// ---- passA body: LDS bucket histogram + per-(block,bucket) reservation ----
__device__ __forceinline__ void passA_body(
    int blk, const int* __restrict__ src, const int* __restrict__ dst,
    int E, int N, int* __restrict__ bktcnt, int* __restrict__ lbase_g, int nbkt)
{
    __shared__ int lcnt[NB_MAX];
    int tid = threadIdx.x;
    int EN = E + N;
    int base = blk * 4096;
    for (int b = tid; b < nbkt; b += 256) lcnt[b] = 0;
    __syncthreads();
    #pragma unroll
    for (int j = 0; j < 16; j++) {
        int i = base + j * 256 + tid;
        if (i < EN) {
            int d = (i < E) ? dst[i] : (i - E);
            atomicAdd(&lcnt[d >> BKT_SH], 1);
        }
    }
    __syncthreads();
    for (int b = tid; b < nbkt; b += 256) {
        int c = lcnt[b];
        lbase_g[(size_t)blk * nbkt + b] = c ? atomicAdd(&bktcnt[b], c) : 0;
    }
}

// ---- fused: gemm1 (blocks [0, 2*nbG)) || passA (rest) ----
__global__ void __launch_bounds__(256) gemm1_passA_kernel(
    const float* __restrict__ X, const _Float16* __restrict__ WTH,
    const float* __restrict__ atts, const float* __restrict__ attd,
    _Float16* __restrict__ OUT, float* __restrict__ oas, float* __restrict__ oad,
    int N, int nbG,
    const int* __restrict__ src, const int* __restrict__ dst, int E,
    int* __restrict__ bktcnt, int* __restrict__ lbase_g, int nbkt)
{
    if ((int)blockIdx.x < 2 * nbG) {
        gemm_att_body<0>(blockIdx.x % nbG, blockIdx.x / nbG, X, WTH, atts, attd,
                         OUT, oas, oad, N, 128, 4, 5);
    } else {
        passA_body((int)blockIdx.x - 2 * nbG, src, dst, E, N, bktcnt, lbase_g, nbkt);
    }
}

__global__ void __launch_bounds__(256) gemm2_kernel(
    const _Float16* __restrict__ X, const _Float16* __restrict__ WTH,
    const float* __restrict__ atts, const float* __restrict__ attd,
    _Float16* __restrict__ OUT, float* __restrict__ oas, float* __restrict__ oad,
    int N)
{
    gemm_att_body<1>(blockIdx.x, 0, X, WTH, atts, attd, OUT, oas, oad,
                     N, 64, 1, 6);
}

// ---- bucket-count scan: 391 entries, one 512-thread block ----
__global__ void __launch_bounds__(512) scanb_kernel(
    const int* __restrict__ bktcnt, int* __restrict__ bktoff, int nbkt)
{
    __shared__ int wsum[8];
    int t = threadIdx.x, lane = t & 63, wid = t >> 6;
    int v = (t < nbkt) ? bktcnt[t] : 0;
    #pragma unroll
    for (int off = 1; off < 64; off <<= 1) {
        int y = __shfl_up(v, off);
        if (lane >= off) v += y;
    }
    if (lane == 63) wsum[wid] = v;
    __syncthreads();
    if (wid == 0) {
        int s = (lane < 8) ? wsum[lane] : 0;
        #pragma unroll
        for (int off = 1; off < 8; off <<= 1) {
            int y = __shfl_up(s, off);
            if (lane >= off) s += y;
        }
        if (lane < 8) wsum[lane] = s;
    }
    __syncthreads();
    if (wid > 0) v += wsum[wid - 1];
    if (t < nbkt) bktoff[t + 1] = v;
    if (t == 0) bktoff[0] = 0;
}

// ---- passB: write bucket-major (d,s) runs via LDS cursors ----
__global__ void __launch_bounds__(256) passB_kernel(
    const int* __restrict__ src, const int* __restrict__ dst, int E, int N,
    const int* __restrict__ bktoff, const int* __restrict__ lbase_g,
    uint2* __restrict__ ebuf, int nbkt)
{
    __shared__ int sbase[NB_MAX];
    __shared__ int loff[NB_MAX];
    int blk = blockIdx.x;
    int tid = threadIdx.x;
    int EN = E + N;
    int base = blk * 4096;
    for (int b = tid; b < nbkt; b += 256) {
        sbase[b] = bktoff[b] + lbase_g[(size_t)blk * nbkt + b];
        loff[b] = 0;
    }
    __syncthreads();
    #pragma unroll
    for (int j = 0; j < 16; j++) {
        int i = base + j * 256 + tid;
        if (i < EN) {
            int s, d;
            if (i < E) { s = src[i]; d = dst[i]; } else { s = d = i - E; }
            int b = d >> BKT_SH;
            int off = atomicAdd(&loff[b], 1);
            ebuf[(size_t)sbase[b] + off] = make_uint2((unsigned)d, (unsigned)s);
        }
    }
}

// ---- build: per-bucket node hist + in-block scan -> rowp + csrs ----
__global__ void __launch_bounds__(256) build_kernel(
    const uint2* __restrict__ ebuf, const int* __restrict__ bktoff,
    int* __restrict__ rowp, int* __restrict__ csrs, int N, int nbkt)
{
    __shared__ int ldeg[128];
    __shared__ int lrow[129];
    __shared__ int lcur[128];
    __shared__ int w0tot;
    int b = blockIdx.x;
    if (b >= nbkt) return;
    int n0 = b << BKT_SH;
    int n1 = n0 + 128; if (n1 > N) n1 = N;
    int r0 = bktoff[b], r1 = bktoff[b + 1];
    int t = threadIdx.x;
    if (t < 128) { ldeg[t] = 0; lcur[t] = 0; }
    __syncthreads();
    for (int i = r0 + t; i < r1; i += 256)
        atomicAdd(&ldeg[(int)ebuf[i].x - n0], 1);
    __syncthreads();
    int lane = t & 63;
    int v = (t < 128) ? ldeg[t] : 0;
    #pragma unroll
    for (int off = 1; off < 64; off <<= 1) {
        int y = __shfl_up(v, off);
        if (lane >= off) v += y;
    }
    if (t == 63) w0tot = v;
    __syncthreads();
    if (t >= 64 && t < 128) v += w0tot;
    if (t < 128) lrow[t + 1] = v;
    if (t == 0) { lrow[0] = 0; rowp[n0] = r0; }
    if (t < n1 - n0) rowp[n0 + t + 1] = r0 + v;
    __syncthreads();
    for (int i = r0 + t; i < r1; i += 256) {
        uint2 e = ebuf[i];
        int d = (int)e.x - n0;
        int pos = r0 + lrow[d] + atomicAdd(&lcur[d], 1);
        csrs[pos] = (int)e.y;
    }
}

// ---- edge1 chunk: K-slot staged gather + FMA (padding clamps/zeros) ----
template<int K>
__device__ __forceinline__ void chunk1(
    const int* __restrict__ csr, int base, int cnt,
    const float* __restrict__ as1, float adv,
    int el, int hh, int hd, int lane, const __half2* __restrict__ h1,
    float& accx, float& accy, float& srun)
{
    float wvA = 0.f, wvB = 0.f;
    if (el < cnt) {
        int s = csr[base + el];
        float e = as1[s * 4 + hh] + adv;
        e = e > 0.f ? e : LRELU_SLOPE * e;
        wvA = __expf(e);
    }
    if (K > 16 && el + 16 < cnt) {
        int s = csr[base + 16 + el];
        float e = as1[s * 4 + hh] + adv;
        e = e > 0.f ? e : LRELU_SLOPE * e;
        wvB = __expf(e);
    }
    float t = wvA + wvB;
    t += __shfl_xor(t, 4);  t += __shfl_xor(t, 8);
    t += __shfl_xor(t, 16); t += __shfl_xor(t, 32);
    srun += t;
    __half2 hv[K];
    #pragma unroll
    for (int e2 = 0; e2 < K; ++e2) {
        int ee = e2 < cnt ? e2 : cnt - 1;      // wave-uniform clamp
        int s = csr[base + ee];                // uniform -> s_load
        hv[e2] = h1[(size_t)s * 64 + lane];
    }
    #pragma unroll
    for (int e2 = 0; e2 < K; ++e2) {
        float av = (e2 < 16) ? __shfl(wvA, (e2 << 2) | hd)
                             : __shfl(wvB, ((e2 - 16) << 2) | hd);
        float2 v = __half22float2(hv[e2]);
        accx = fmaf(av, v.x, accx);
        accy = fmaf(av, v.y, accy);
    }
}

// ---- layer-1 edge pass: one wave per node; 32-slot chunks + sized tail ----
__global__ void __launch_bounds__(256) edge1_kernel(
    const int* __restrict__ csr, const int* __restrict__ rowp,
    const __half2* __restrict__ h1, const float* __restrict__ as1,
    const float* __restrict__ ad1, const float* __restrict__ b1,
    __half* __restrict__ x2h, int N)
{
    int lane = threadIdx.x & 63;
    int n = __builtin_amdgcn_readfirstlane(blockIdx.x * 4 + (threadIdx.x >> 6));
    if (n >= N) return;
    int rs = rowp[n], re = rowp[n + 1];
    int hd = lane >> 4;
    int el = lane >> 2, hh = lane & 3;
    float adv = ad1[n * 4 + hh];
    float accx = 0.f, accy = 0.f, srun = 0.f;
    int base = rs, rem = re - rs;
    while (rem >= 32) {
        chunk1<32>(csr, base, 32, as1, adv, el, hh, hd, lane, h1, accx, accy, srun);
        base += 32; rem -= 32;
    }
    if (rem > 24)      chunk1<32>(csr, base, rem, as1, adv, el, hh, hd, lane, h1, accx, accy, srun);
    else if (rem > 16) chunk1<24>(csr, base, rem, as1, adv, el, hh, hd, lane, h1, accx, accy, srun);
    else if (rem > 8)  chunk1<16>(csr, base, rem, as1, adv, el, hh, hd, lane, h1, accx, accy, srun);
    else if (rem > 0)  chunk1<8> (csr, base, rem, as1, adv, el, hh, hd, lane, h1, accx, accy, srun);

    float sden = __shfl(srun, hd) + 1e-16f;
    float inv = 1.f / sden;
    float2 bv = *(const float2*)(b1 + lane * 2);
    float o0 = accx * inv + bv.x;
    float o1 = accy * inv + bv.y;
    o0 = o0 > 0.f ? o0 : (__expf(o0) - 1.f);   // ELU
    o1 = o1 > 0.f ? o1 : (__expf(o1) - 1.f);
    *(__half2*)(x2h + (size_t)n * 128 + lane * 2) = __floats2half2_rn(o0, o1);
}

// ---- edge2 chunk: K-slot staged gather (K <= 16) ----
template<int K>
__device__ __forceinline__ void chunk2(
    const int* __restrict__ csr, int base, int cnt,
    const float* __restrict__ as2, float adv, int lane,
    const __half* __restrict__ h2, float& acc, float& srun)
{
    float wv = 0.f;
    if (lane < cnt) {
        int s = csr[base + lane];
        float e = as2[s] + adv;
        e = e > 0.f ? e : LRELU_SLOPE * e;
        wv = __expf(e);
    }
    srun += wv;
    __half hv[K];
    #pragma unroll
    for (int e2 = 0; e2 < K; ++e2) {
        int ee = e2 < cnt ? e2 : cnt - 1;      // wave-uniform clamp
        int s = csr[base + ee];                // uniform -> s_load
        hv[e2] = h2[(size_t)s * 64 + lane];
    }
    #pragma unroll
    for (int e2 = 0; e2 < K; ++e2) {
        float av = __shfl(wv, e2);             // 0 for padded slots
        acc = fmaf(av, __half2float(hv[e2]), acc);
    }
}

// ---- layer-2 edge pass (1 head, 64 channels; lane = channel) ----
__global__ void __launch_bounds__(256) edge2_kernel(
    const int* __restrict__ csr, const int* __restrict__ rowp,
    const __half* __restrict__ h2, const float* __restrict__ as2,
    const float* __restrict__ ad2, const float* __restrict__ b2,
    float* __restrict__ hf, int N)
{
    int lane = threadIdx.x & 63;
    int n = __builtin_amdgcn_readfirstlane(blockIdx.x * 4 + (threadIdx.x >> 6));
    if (n >= N) return;
    int rs = rowp[n], re = rowp[n + 1];
    float adv = ad2[n];
    float acc = 0.f, srun = 0.f;
    int base = rs, rem = re - rs;
    while (rem >= 16) {
        chunk2<16>(csr, base, 16, as2, adv, lane, h2, acc, srun);
        base += 16; rem -= 16;
    }
    if (rem > 8)      chunk2<16>(csr, base, rem, as2, adv, lane, h2, acc, srun);
    else if (rem > 0) chunk2<8> (csr, base, rem, as2, adv, lane, h2, acc, srun);

    #pragma unroll
    for (int m = 1; m < 64; m <<= 1) srun += __shfl_xor(srun, m);
    float o = acc / (srun + 1e-16f) + b2[lane];
    hf[(size_t)n * 64 + lane] = o;
}

// ---- per-node MLP projections: u|v = hf[n] @ Wm1 halves; uv fp16 ----
__global__ void __launch_bounds__(256) node_mlp_kernel(
    const float* __restrict__ hf, const float* __restrict__ Wm1T,
    __half* __restrict__ uv, int N)
{
    int lane = threadIdx.x & 63;
    int j = lane & 31, half = lane >> 5;
    const float* wr = Wm1T + j * 128 + half * 64;
    float wreg[64];
    #pragma unroll
    for (int q = 0; q < 16; q++) {
        float4 t = ((const float4*)wr)[q];
        wreg[q*4] = t.x; wreg[q*4+1] = t.y; wreg[q*4+2] = t.z; wreg[q*4+3] = t.w;
    }
    int wgid = __builtin_amdgcn_readfirstlane(blockIdx.x * 4 + (threadIdx.x >> 6));
    int nwaves = gridDim.x * 4;
    for (int n = wgid; n < N; n += nwaves) {
        const float* hr = hf + (size_t)n * 64;
        float acc = 0.f;
        #pragma unroll
        for (int k = 0; k < 64; k += 4) {
            float4 hv = *(const float4*)(hr + k);   // uniform across wave
            acc = fmaf(hv.x, wreg[k],   acc);
            acc = fmaf(hv.y, wreg[k+1], acc);
            acc = fmaf(hv.z, wreg[k+2], acc);
            acc = fmaf(hv.w, wreg[k+3], acc);
        }
        uv[(size_t)n * 64 + lane] = __float2half_rn(acc);
    }
}

// ---- pair MLP: 2 lanes per pair (16 hidden units each), shfl-reduce ----
__global__ void __launch_bounds__(256) pair_mlp_kernel(
    const int* __restrict__ ps, const int* __restrict__ pd,
    const __half2* __restrict__ uv, const float* __restrict__ bm1,
    const float* __restrict__ Wm2, const float* __restrict__ bm2,
    float* __restrict__ out, int P)
{
    int gid = blockIdx.x * 256 + threadIdx.x;
    int p = gid >> 1;
    if (p >= P) return;
    int half = gid & 1;
    int j0 = half * 8;
    int a = ps[p], b = pd[p];
    const __half2* ua = uv + (size_t)a * 32 + j0;
    const __half2* vb = uv + (size_t)b * 32 + 16 + j0;
    float r = 0.f;
    #pragma unroll
    for (int q = 0; q < 8; q++) {
        float2 uu = __half22float2(ua[q]);
        float2 vv = __half22float2(vb[q]);
        float2 bb = *(const float2*)(bm1 + half * 16 + q * 2);
        float2 ww = *(const float2*)(Wm2 + half * 16 + q * 2);
        float h0 = uu.x + vv.x + bb.x; h0 = h0 > 0.f ? h0 : 0.f; r = fmaf(h0, ww.x, r);
        float h1 = uu.y + vv.y + bb.y; h1 = h1 > 0.f ? h1 : 0.f; r = fmaf(h1, ww.y, r);
    }
    r += __shfl_xor(r, 1);
    if (half == 0) out[p] = r + bm2[0];
}

extern "C" void kernel_launch(void* const* d_in, const int* in_sizes, int n_in,
                              void* d_out, int out_size, void* d_ws, size_t ws_size,
                              hipStream_t stream)
{
    const float* x    = (const float*)d_in[0];
    const int*   ei   = (const int*)  d_in[1];
    const int*   ep   = (const int*)  d_in[2];
    const float* W1   = (const float*)d_in[3];
    const float* atS1 = (const float*)d_in[4];
    const float* atD1 = (const float*)d_in[5];
    const float* b1   = (const float*)d_in[6];
    const float* W2   = (const float*)d_in[7];
    const float* atS2 = (const float*)d_in[8];
    const float* atD2 = (const float*)d_in[9];
    const float* b2   = (const float*)d_in[10];
    const float* Wm1  = (const float*)d_in[11];
    const float* bm1  = (const float*)d_in[12];
    const float* Wm2  = (const float*)d_in[13];
    const float* bm2  = (const float*)d_in[14];
    float* out = (float*)d_out;

    int N = in_sizes[0] / 128;
    int E = in_sizes[1] / 2;
    int P = in_sizes[2] / 2;
    int Etot = E + N;
    int EN = Etot;
    int nbkt = (N + (1 << BKT_SH) - 1) >> BKT_SH;
    int nbA  = (EN + 4095) / 4096;

    // workspace carve (256B aligned)
    char* w = (char*)d_ws;
    auto alloc = [&](size_t bytes) {
        char* p = w; w += (bytes + 255) & ~(size_t)255; return p;
    };
    _Float16* W1Th = (_Float16*)alloc(16384 * 2);
    _Float16* W2Th = (_Float16*)alloc(8192 * 2);
    float*    Wm1T = (float*)alloc(4096 * 4);
    _Float16* h1   = (_Float16*)alloc((size_t)N * 128 * 2);  // fp16
    __half*   x2h  = (__half*)alloc((size_t)N * 128 * 2);    // fp16
    _Float16* h2   = (_Float16*)alloc((size_t)N * 64 * 2);   // fp16
    float*    hf   = (float*)alloc((size_t)N * 64 * 4);
    int*      rowp = (int*)alloc((size_t)(N + 1) * 4);
    int*      bktoff = (int*)alloc((size_t)(nbkt + 1) * 4);
    int*      csrs = (int*)alloc((size_t)Etot * 4);
    uint2*    ebuf = (uint2*)alloc((size_t)Etot * 8);
    int*      lbase_g = (int*)alloc((size_t)nbA * nbkt * 4);
    // ---- contiguous zero-block (zeroed in zero_prep_kernel) ----
    char* z0 = w;
    int*   bktcnt = (int*)alloc(NB_MAX * 4);
    char* z1 = w;
    float* as1  = (float*)alloc((size_t)N * 4 * 4);
    float* ad1  = (float*)alloc((size_t)N * 4 * 4);
    float* as2  = (float*)alloc((size_t)N * 4);
    float* ad2  = (float*)alloc((size_t)N * 4);
    __half* uv = (__half*)alloc((size_t)N * 64 * 2);

    int zn4 = (int)((z1 - z0) / 16);
    zero_prep_kernel<<<112, 256, 0, stream>>>(W1, W2, Wm1, W1Th, W2Th, Wm1T,
                                              (uint4*)z0, zn4);

    int nbG = (N + 63) / 64;
    gemm1_passA_kernel<<<2 * nbG + nbA, 256, 0, stream>>>(
        x, W1Th, atS1, atD1, h1, as1, ad1, N, nbG,
        ei, ei + E, E, bktcnt, lbase_g, nbkt);

    scanb_kernel<<<1, 512, 0, stream>>>(bktcnt, bktoff, nbkt);
    passB_kernel<<<nbA, 256, 0, stream>>>(ei, ei + E, E, N, bktoff, lbase_g,
                                          ebuf, nbkt);
    build_kernel<<<nbkt, 256, 0, stream>>>(ebuf, bktoff, rowp, csrs, N, nbkt);

    edge1_kernel<<<(N + 3) / 4, 256, 0, stream>>>(csrs, rowp, (const __half2*)h1,
                                                  as1, ad1, b1, x2h, N);
    gemm2_kernel<<<nbG, 256, 0, stream>>>((const _Float16*)x2h, W2Th, atS2, atD2,
                                          h2, as2, ad2, N);
    edge2_kernel<<<(N + 3) / 4, 256, 0, stream>>>(csrs, rowp, (const __half*)h2,
                                                  as2, ad2, b2, hf, N);

    node_mlp_kernel<<<1024, 256, 0, stream>>>(hf, Wm1T, uv, N);
    pair_mlp_kernel<<<(2 * P + 255) / 256, 256, 0, stream>>>(ep, ep + P,
                                                             (const __half2*)uv,
                                                             bm1, Wm2, bm2, out, P);
}

// Round 19
// 169.024 us; speedup vs baseline: 1.5460x; 1.0014x over previous
//
#include <hip/hip_runtime.h>
#include <hip/hip_bf16.h>
#include <hip/hip_fp16.h>

// ---------------------------------------------------------------------------
// GAT link predictor: 2x GATConv + pair MLP.
// R19: restore R17 verbatim (169.3us, absmax 6.1e-5) after R18's cooperative
//      launch failed under the harness (kernels never ran). This is the
//      verified configuration: gemm1||passA fusion, atomic-reservation CSR
//      build (scanb/passB/build), MFMA f16 GEMMs, fp16 gather tables,
//      32-slot+tail edge1, 16-slot edge2, factorized MLP. 10 launches.
// ---------------------------------------------------------------------------

#define LRELU_SLOPE 0.2f
#define BKT_SH 7
#define NB_MAX 512

typedef _Float16 v8h __attribute__((ext_vector_type(8)));
typedef float    v4f __attribute__((ext_vector_type(4)));

// ---- fused zero (bktcnt block) + weight prep ----
__global__ void __launch_bounds__(256) zero_prep_kernel(
    const float* __restrict__ W1, const float* __restrict__ W2,
    const float* __restrict__ Wm1,
    _Float16* __restrict__ W1Th, _Float16* __restrict__ W2Th,
    float* __restrict__ Wm1T, uint4* __restrict__ zp, int zn4)
{
    int i = blockIdx.x * 256 + threadIdx.x;
    if (i < zn4) zp[i] = make_uint4(0u, 0u, 0u, 0u);
    if (i < 16384) {                       // W1 [128][128] -> W1Th [128][128]
        int k = i >> 7, j = i & 127;
        W1Th[j * 128 + k] = (_Float16)W1[i];
    } else if (i < 16384 + 8192) {         // W2 [128][64] -> W2Th [64][128]
        int t = i - 16384;
        int k = t >> 6, j = t & 63;
        W2Th[j * 128 + k] = (_Float16)W2[t];
    } else if (i < 16384 + 8192 + 4096) {  // Wm1 [128][32] -> Wm1T [32][128]
        int t = i - 24576;
        int k = t >> 5, j = t & 31;
        Wm1T[j * 128 + k] = Wm1[t];
    }
}

// ---- MFMA f16 GEMM + fused attention scores (device body) ----
// Wave = 16 rows x 64 cols. A frag: row=lane&15, k=(lane>>4)*8+j.
// B frag: col=lane&15, same k. C/D: col=lane&15, row=(lane>>4)*4+reg.
template<int AHALF>
__device__ __forceinline__ void gemm_att_body(
    int bx, int by,
    const void* __restrict__ Xv, const _Float16* __restrict__ WTH,
    const float* __restrict__ atts, const float* __restrict__ attd,
    _Float16* __restrict__ OUT, float* __restrict__ oas, float* __restrict__ oad,
    int N, int ncols, int H, int headShift)
{
    __shared__ _Float16 cs[64 * 68];
    int tid = threadIdx.x;
    int lane = tid & 63;
    int wv = tid >> 6;
    int rowBase = bx * 64 + wv * 16;
    int colBase = by * 64;
    int lr = lane & 15;
    int lk = lane >> 4;

    v8h bf[4][4];
    #pragma unroll
    for (int ct = 0; ct < 4; ct++) {
        const _Float16* bp = WTH + (size_t)(colBase + ct * 16 + lr) * 128 + lk * 8;
        #pragma unroll
        for (int ks = 0; ks < 4; ks++)
            bf[ct][ks] = *(const v8h*)(bp + ks * 32);
    }

    int arow = rowBase + lr;
    if (arow >= N) arow = N - 1;            // clamp; stores masked below
    v4f acc[4];
    #pragma unroll
    for (int ct = 0; ct < 4; ct++) acc[ct] = (v4f){0.f, 0.f, 0.f, 0.f};

    if (AHALF) {
        const _Float16* ap = (const _Float16*)Xv + (size_t)arow * 128 + lk * 8;
        #pragma unroll
        for (int ks = 0; ks < 4; ks++) {
            v8h af = *(const v8h*)(ap + ks * 32);
            #pragma unroll
            for (int ct = 0; ct < 4; ct++)
                acc[ct] = __builtin_amdgcn_mfma_f32_16x16x32_f16(af, bf[ct][ks],
                                                                 acc[ct], 0, 0, 0);
        }
    } else {
        const float* ap = (const float*)Xv + (size_t)arow * 128 + lk * 8;
        #pragma unroll
        for (int ks = 0; ks < 4; ks++) {
            float4 a0 = *(const float4*)(ap + ks * 32);
            float4 a1 = *(const float4*)(ap + ks * 32 + 4);
            v8h af;
            af[0] = (_Float16)a0.x; af[1] = (_Float16)a0.y;
            af[2] = (_Float16)a0.z; af[3] = (_Float16)a0.w;
            af[4] = (_Float16)a1.x; af[5] = (_Float16)a1.y;
            af[6] = (_Float16)a1.z; af[7] = (_Float16)a1.w;
            #pragma unroll
            for (int ct = 0; ct < 4; ct++)
                acc[ct] = __builtin_amdgcn_mfma_f32_16x16x32_f16(af, bf[ct][ks],
                                                                 acc[ct], 0, 0, 0);
        }
    }

    int ctPerHead = (1 << headShift) >> 4;        // 2 (L1) or 4 (L2)
    #pragma unroll
    for (int hh = 0; hh < 2; hh++) {
        if (hh * ctPerHead >= 4) break;
        float ps[4] = {0.f, 0.f, 0.f, 0.f};
        float pd[4] = {0.f, 0.f, 0.f, 0.f};
        for (int c2 = 0; c2 < ctPerHead; c2++) {
            int ct = hh * ctPerHead + c2;
            int col = colBase + ct * 16 + lr;
            float ws = atts[col], wd = attd[col];
            #pragma unroll
            for (int r = 0; r < 4; r++) {
                ps[r] = fmaf(acc[ct][r], ws, ps[r]);
                pd[r] = fmaf(acc[ct][r], wd, pd[r]);
            }
        }
        #pragma unroll
        for (int r = 0; r < 4; r++) {
            #pragma unroll
            for (int m = 1; m < 16; m <<= 1) {
                ps[r] += __shfl_xor(ps[r], m);
                pd[r] += __shfl_xor(pd[r], m);
            }
        }
        if (lr == 0) {
            int head = (colBase >> headShift) + hh;
            #pragma unroll
            for (int r = 0; r < 4; r++) {
                int row = rowBase + lk * 4 + r;
                if (row < N) {
                    oas[(size_t)row * H + head] = ps[r];
                    oad[(size_t)row * H + head] = pd[r];
                }
            }
        }
    }

    #pragma unroll
    for (int ct = 0; ct < 4; ct++)
        #pragma unroll
        for (int r = 0; r < 4; r++)
            cs[(wv * 16 + lk * 4 + r) * 68 + ct * 16 + lr] = (_Float16)acc[ct][r];
    __syncthreads();
    int rr = tid >> 2;
    int cb = (tid & 3) * 16;
    int grow = bx * 64 + rr;
    if (grow < N) {
        const uint4* sp = (const uint4*)(cs + rr * 68 + cb);
        _Float16* op = OUT + (size_t)grow * ncols + colBase + cb;
        uint4 w0 = sp[0];
        uint4 w1 = sp[1];
        *(uint4*)op = w0;
        *(uint4*)(op + 8) = w1;
    }
}

// ---- passA body: LDS bucket histogram + per-(block,bucket) reservation ----
__device__ __forceinline__ void passA_body(
    int blk, const int* __restrict__ src, const int* __restrict__ dst,
    int E, int N, int* __restrict__ bktcnt, int* __restrict__ lbase_g, int nbkt)
{
    __shared__ int lcnt[NB_MAX];
    int tid = threadIdx.x;
    int EN = E + N;
    int base = blk * 4096;
    for (int b = tid; b < nbkt; b += 256) lcnt[b] = 0;
    __syncthreads();
    #pragma unroll
    for (int j = 0; j < 16; j++) {
        int i = base + j * 256 + tid;
        if (i < EN) {
            int d = (i < E) ? dst[i] : (i - E);
            atomicAdd(&lcnt[d >> BKT_SH], 1);
        }
    }
    __syncthreads();
    for (int b = tid; b < nbkt; b += 256) {
        int c = lcnt[b];
        lbase_g[(size_t)blk * nbkt + b] = c ? atomicAdd(&bktcnt[b], c) : 0;
    }
}

// ---- fused: gemm1 (blocks [0, 2*nbG)) || passA (rest) ----
__global__ void __launch_bounds__(256) gemm1_passA_kernel(
    const float* __restrict__ X, const _Float16* __restrict__ WTH,
    const float* __restrict__ atts, const float* __restrict__ attd,
    _Float16* __restrict__ OUT, float* __restrict__ oas, float* __restrict__ oad,
    int N, int nbG,
    const int* __restrict__ src, const int* __restrict__ dst, int E,
    int* __restrict__ bktcnt, int* __restrict__ lbase_g, int nbkt)
{
    if ((int)blockIdx.x < 2 * nbG) {
        gemm_att_body<0>(blockIdx.x % nbG, blockIdx.x / nbG, X, WTH, atts, attd,
                         OUT, oas, oad, N, 128, 4, 5);
    } else {
        passA_body((int)blockIdx.x - 2 * nbG, src, dst, E, N, bktcnt, lbase_g, nbkt);
    }
}

__global__ void __launch_bounds__(256) gemm2_kernel(
    const _Float16* __restrict__ X, const _Float16* __restrict__ WTH,
    const float* __restrict__ atts, const float* __restrict__ attd,
    _Float16* __restrict__ OUT, float* __restrict__ oas, float* __restrict__ oad,
    int N)
{
    gemm_att_body<1>(blockIdx.x, 0, X, WTH, atts, attd, OUT, oas, oad,
                     N, 64, 1, 6);
}

// ---- bucket-count scan: 391 entries, one 512-thread block ----
__global__ void __launch_bounds__(512) scanb_kernel(
    const int* __restrict__ bktcnt, int* __restrict__ bktoff, int nbkt)
{
    __shared__ int wsum[8];
    int t = threadIdx.x, lane = t & 63, wid = t >> 6;
    int v = (t < nbkt) ? bktcnt[t] : 0;
    #pragma unroll
    for (int off = 1; off < 64; off <<= 1) {
        int y = __shfl_up(v, off);
        if (lane >= off) v += y;
    }
    if (lane == 63) wsum[wid] = v;
    __syncthreads();
    if (wid == 0) {
        int s = (lane < 8) ? wsum[lane] : 0;
        #pragma unroll
        for (int off = 1; off < 8; off <<= 1) {
            int y = __shfl_up(s, off);
            if (lane >= off) s += y;
        }
        if (lane < 8) wsum[lane] = s;
    }
    __syncthreads();
    if (wid > 0) v += wsum[wid - 1];
    if (t < nbkt) bktoff[t + 1] = v;
    if (t == 0) bktoff[0] = 0;
}

// ---- passB: write bucket-major (d,s) runs via LDS cursors ----
__global__ void __launch_bounds__(256) passB_kernel(
    const int* __restrict__ src, const int* __restrict__ dst, int E, int N,
    const int* __restrict__ bktoff, const int* __restrict__ lbase_g,
    uint2* __restrict__ ebuf, int nbkt)
{
    __shared__ int sbase[NB_MAX];
    __shared__ int loff[NB_MAX];
    int blk = blockIdx.x;
    int tid = threadIdx.x;
    int EN = E + N;
    int base = blk * 4096;
    for (int b = tid; b < nbkt; b += 256) {
        sbase[b] = bktoff[b] + lbase_g[(size_t)blk * nbkt + b];
        loff[b] = 0;
    }
    __syncthreads();
    #pragma unroll
    for (int j = 0; j < 16; j++) {
        int i = base + j * 256 + tid;
        if (i < EN) {
            int s, d;
            if (i < E) { s = src[i]; d = dst[i]; } else { s = d = i - E; }
            int b = d >> BKT_SH;
            int off = atomicAdd(&loff[b], 1);
            ebuf[(size_t)sbase[b] + off] = make_uint2((unsigned)d, (unsigned)s);
        }
    }
}

// ---- build: per-bucket node hist + in-block scan -> rowp + csrs ----
__global__ void __launch_bounds__(256) build_kernel(
    const uint2* __restrict__ ebuf, const int* __restrict__ bktoff,
    int* __restrict__ rowp, int* __restrict__ csrs, int N, int nbkt)
{
    __shared__ int ldeg[128];
    __shared__ int lrow[129];
    __shared__ int lcur[128];
    __shared__ int w0tot;
    int b = blockIdx.x;
    if (b >= nbkt) return;
    int n0 = b << BKT_SH;
    int n1 = n0 + 128; if (n1 > N) n1 = N;
    int r0 = bktoff[b], r1 = bktoff[b + 1];
    int t = threadIdx.x;
    if (t < 128) { ldeg[t] = 0; lcur[t] = 0; }
    __syncthreads();
    for (int i = r0 + t; i < r1; i += 256)
        atomicAdd(&ldeg[(int)ebuf[i].x - n0], 1);
    __syncthreads();
    int lane = t & 63;
    int v = (t < 128) ? ldeg[t] : 0;
    #pragma unroll
    for (int off = 1; off < 64; off <<= 1) {
        int y = __shfl_up(v, off);
        if (lane >= off) v += y;
    }
    if (t == 63) w0tot = v;
    __syncthreads();
    if (t >= 64 && t < 128) v += w0tot;
    if (t < 128) lrow[t + 1] = v;
    if (t == 0) { lrow[0] = 0; rowp[n0] = r0; }
    if (t < n1 - n0) rowp[n0 + t + 1] = r0 + v;
    __syncthreads();
    for (int i = r0 + t; i < r1; i += 256) {
        uint2 e = ebuf[i];
        int d = (int)e.x - n0;
        int pos = r0 + lrow[d] + atomicAdd(&lcur[d], 1);
        csrs[pos] = (int)e.y;
    }
}

// ---- edge1 chunk: K-slot staged gather + FMA (padding clamps/zeros) ----
template<int K>
__device__ __forceinline__ void chunk1(
    const int* __restrict__ csr, int base, int cnt,
    const float* __restrict__ as1, float adv,
    int el, int hh, int hd, int lane, const __half2* __restrict__ h1,
    float& accx, float& accy, float& srun)
{
    float wvA = 0.f, wvB = 0.f;
    if (el < cnt) {
        int s = csr[base + el];
        float e = as1[s * 4 + hh] + adv;
        e = e > 0.f ? e : LRELU_SLOPE * e;
        wvA = __expf(e);
    }
    if (K > 16 && el + 16 < cnt) {
        int s = csr[base + 16 + el];
        float e = as1[s * 4 + hh] + adv;
        e = e > 0.f ? e : LRELU_SLOPE * e;
        wvB = __expf(e);
    }
    float t = wvA + wvB;
    t += __shfl_xor(t, 4);  t += __shfl_xor(t, 8);
    t += __shfl_xor(t, 16); t += __shfl_xor(t, 32);
    srun += t;
    __half2 hv[K];
    #pragma unroll
    for (int e2 = 0; e2 < K; ++e2) {
        int ee = e2 < cnt ? e2 : cnt - 1;      // wave-uniform clamp
        int s = csr[base + ee];                // uniform -> s_load
        hv[e2] = h1[(size_t)s * 64 + lane];
    }
    #pragma unroll
    for (int e2 = 0; e2 < K; ++e2) {
        float av = (e2 < 16) ? __shfl(wvA, (e2 << 2) | hd)
                             : __shfl(wvB, ((e2 - 16) << 2) | hd);
        float2 v = __half22float2(hv[e2]);
        accx = fmaf(av, v.x, accx);
        accy = fmaf(av, v.y, accy);
    }
}

// ---- layer-1 edge pass: one wave per node; 32-slot chunks + sized tail ----
__global__ void __launch_bounds__(256) edge1_kernel(
    const int* __restrict__ csr, const int* __restrict__ rowp,
    const __half2* __restrict__ h1, const float* __restrict__ as1,
    const float* __restrict__ ad1, const float* __restrict__ b1,
    __half* __restrict__ x2h, int N)
{
    int lane = threadIdx.x & 63;
    int n = __builtin_amdgcn_readfirstlane(blockIdx.x * 4 + (threadIdx.x >> 6));
    if (n >= N) return;
    int rs = rowp[n], re = rowp[n + 1];
    int hd = lane >> 4;
    int el = lane >> 2, hh = lane & 3;
    float adv = ad1[n * 4 + hh];
    float accx = 0.f, accy = 0.f, srun = 0.f;
    int base = rs, rem = re - rs;
    while (rem >= 32) {
        chunk1<32>(csr, base, 32, as1, adv, el, hh, hd, lane, h1, accx, accy, srun);
        base += 32; rem -= 32;
    }
    if (rem > 24)      chunk1<32>(csr, base, rem, as1, adv, el, hh, hd, lane, h1, accx, accy, srun);
    else if (rem > 16) chunk1<24>(csr, base, rem, as1, adv, el, hh, hd, lane, h1, accx, accy, srun);
    else if (rem > 8)  chunk1<16>(csr, base, rem, as1, adv, el, hh, hd, lane, h1, accx, accy, srun);
    else if (rem > 0)  chunk1<8> (csr, base, rem, as1, adv, el, hh, hd, lane, h1, accx, accy, srun);

    float sden = __shfl(srun, hd) + 1e-16f;
    float inv = 1.f / sden;
    float2 bv = *(const float2*)(b1 + lane * 2);
    float o0 = accx * inv + bv.x;
    float o1 = accy * inv + bv.y;
    o0 = o0 > 0.f ? o0 : (__expf(o0) - 1.f);   // ELU
    o1 = o1 > 0.f ? o1 : (__expf(o1) - 1.f);
    *(__half2*)(x2h + (size_t)n * 128 + lane * 2) = __floats2half2_rn(o0, o1);
}

// ---- edge2 chunk: K-slot staged gather (K <= 16) ----
template<int K>
__device__ __forceinline__ void chunk2(
    const int* __restrict__ csr, int base, int cnt,
    const float* __restrict__ as2, float adv, int lane,
    const __half* __restrict__ h2, float& acc, float& srun)
{
    float wv = 0.f;
    if (lane < cnt) {
        int s = csr[base + lane];
        float e = as2[s] + adv;
        e = e > 0.f ? e : LRELU_SLOPE * e;
        wv = __expf(e);
    }
    srun += wv;
    __half hv[K];
    #pragma unroll
    for (int e2 = 0; e2 < K; ++e2) {
        int ee = e2 < cnt ? e2 : cnt - 1;      // wave-uniform clamp
        int s = csr[base + ee];                // uniform -> s_load
        hv[e2] = h2[(size_t)s * 64 + lane];
    }
    #pragma unroll
    for (int e2 = 0; e2 < K; ++e2) {
        float av = __shfl(wv, e2);             // 0 for padded slots
        acc = fmaf(av, __half2float(hv[e2]), acc);
    }
}

// ---- layer-2 edge pass (1 head, 64 channels; lane = channel) ----
__global__ void __launch_bounds__(256) edge2_kernel(
    const int* __restrict__ csr, const int* __restrict__ rowp,
    const __half* __restrict__ h2, const float* __restrict__ as2,
    const float* __restrict__ ad2, const float* __restrict__ b2,
    float* __restrict__ hf, int N)
{
    int lane = threadIdx.x & 63;
    int n = __builtin_amdgcn_readfirstlane(blockIdx.x * 4 + (threadIdx.x >> 6));
    if (n >= N) return;
    int rs = rowp[n], re = rowp[n + 1];
    float adv = ad2[n];
    float acc = 0.f, srun = 0.f;
    int base = rs, rem = re - rs;
    while (rem >= 16) {
        chunk2<16>(csr, base, 16, as2, adv, lane, h2, acc, srun);
        base += 16; rem -= 16;
    }
    if (rem > 8)      chunk2<16>(csr, base, rem, as2, adv, lane, h2, acc, srun);
    else if (rem > 0) chunk2<8> (csr, base, rem, as2, adv, lane, h2, acc, srun);

    #pragma unroll
    for (int m = 1; m < 64; m <<= 1) srun += __shfl_xor(srun, m);
    float o = acc / (srun + 1e-16f) + b2[lane];
    hf[(size_t)n * 64 + lane] = o;
}

// ---- per-node MLP projections: u|v = hf[n] @ Wm1 halves; uv fp16 ----
__global__ void __launch_bounds__(256) node_mlp_kernel(
    const float* __restrict__ hf, const float* __restrict__ Wm1T,
    __half* __restrict__ uv, int N)
{
    int lane = threadIdx.x & 63;
    int j = lane & 31, half = lane >> 5;
    const float* wr = Wm1T + j * 128 + half * 64;
    float wreg[64];
    #pragma unroll
    for (int q = 0; q < 16; q++) {
        float4 t = ((const float4*)wr)[q];
        wreg[q*4] = t.x; wreg[q*4+1] = t.y; wreg[q*4+2] = t.z; wreg[q*4+3] = t.w;
    }
    int wgid = __builtin_amdgcn_readfirstlane(blockIdx.x * 4 + (threadIdx.x >> 6));
    int nwaves = gridDim.x * 4;
    for (int n = wgid; n < N; n += nwaves) {
        const float* hr = hf + (size_t)n * 64;
        float acc = 0.f;
        #pragma unroll
        for (int k = 0; k < 64; k += 4) {
            float4 hv = *(const float4*)(hr + k);   // uniform across wave
            acc = fmaf(hv.x, wreg[k],   acc);
            acc = fmaf(hv.y, wreg[k+1], acc);
            acc = fmaf(hv.z, wreg[k+2], acc);
            acc = fmaf(hv.w, wreg[k+3], acc);
        }
        uv[(size_t)n * 64 + lane] = __float2half_rn(acc);
    }
}

// ---- pair MLP: 2 lanes per pair (16 hidden units each), shfl-reduce ----
__global__ void __launch_bounds__(256) pair_mlp_kernel(
    const int* __restrict__ ps, const int* __restrict__ pd,
    const __half2* __restrict__ uv, const float* __restrict__ bm1,
    const float* __restrict__ Wm2, const float* __restrict__ bm2,
    float* __restrict__ out, int P)
{
    int gid = blockIdx.x * 256 + threadIdx.x;
    int p = gid >> 1;
    if (p >= P) return;
    int half = gid & 1;
    int j0 = half * 8;
    int a = ps[p], b = pd[p];
    const __half2* ua = uv + (size_t)a * 32 + j0;
    const __half2* vb = uv + (size_t)b * 32 + 16 + j0;
    float r = 0.f;
    #pragma unroll
    for (int q = 0; q < 8; q++) {
        float2 uu = __half22float2(ua[q]);
        float2 vv = __half22float2(vb[q]);
        float2 bb = *(const float2*)(bm1 + half * 16 + q * 2);
        float2 ww = *(const float2*)(Wm2 + half * 16 + q * 2);
        float h0 = uu.x + vv.x + bb.x; h0 = h0 > 0.f ? h0 : 0.f; r = fmaf(h0, ww.x, r);
        float h1 = uu.y + vv.y + bb.y; h1 = h1 > 0.f ? h1 : 0.f; r = fmaf(h1, ww.y, r);
    }
    r += __shfl_xor(r, 1);
    if (half == 0) out[p] = r + bm2[0];
}

extern "C" void kernel_launch(void* const* d_in, const int* in_sizes, int n_in,
                              void* d_out, int out_size, void* d_ws, size_t ws_size,
                              hipStream_t stream)
{
    const float* x    = (const float*)d_in[0];
    const int*   ei   = (const int*)  d_in[1];
    const int*   ep   = (const int*)  d_in[2];
    const float* W1   = (const float*)d_in[3];
    const float* atS1 = (const float*)d_in[4];
    const float* atD1 = (const float*)d_in[5];
    const float* b1   = (const float*)d_in[6];
    const float* W2   = (const float*)d_in[7];
    const float* atS2 = (const float*)d_in[8];
    const float* atD2 = (const float*)d_in[9];
    const float* b2   = (const float*)d_in[10];
    const float* Wm1  = (const float*)d_in[11];
    const float* bm1  = (const float*)d_in[12];
    const float* Wm2  = (const float*)d_in[13];
    const float* bm2  = (const float*)d_in[14];
    float* out = (float*)d_out;

    int N = in_sizes[0] / 128;
    int E = in_sizes[1] / 2;
    int P = in_sizes[2] / 2;
    int Etot = E + N;
    int EN = Etot;
    int nbkt = (N + (1 << BKT_SH) - 1) >> BKT_SH;
    int nbA  = (EN + 4095) / 4096;

    // workspace carve (256B aligned)
    char* w = (char*)d_ws;
    auto alloc = [&](size_t bytes) {
        char* p = w; w += (bytes + 255) & ~(size_t)255; return p;
    };
    _Float16* W1Th = (_Float16*)alloc(16384 * 2);
    _Float16* W2Th = (_Float16*)alloc(8192 * 2);
    float*    Wm1T = (float*)alloc(4096 * 4);
    _Float16* h1   = (_Float16*)alloc((size_t)N * 128 * 2);  // fp16
    __half*   x2h  = (__half*)alloc((size_t)N * 128 * 2);    // fp16
    _Float16* h2   = (_Float16*)alloc((size_t)N * 64 * 2);   // fp16
    float*    hf   = (float*)alloc((size_t)N * 64 * 4);
    int*      rowp = (int*)alloc((size_t)(N + 1) * 4);
    int*      bktoff = (int*)alloc((size_t)(nbkt + 1) * 4);
    int*      csrs = (int*)alloc((size_t)Etot * 4);
    uint2*    ebuf = (uint2*)alloc((size_t)Etot * 8);
    int*      lbase_g = (int*)alloc((size_t)nbA * nbkt * 4);
    // ---- contiguous zero-block (zeroed in zero_prep_kernel) ----
    char* z0 = w;
    int*   bktcnt = (int*)alloc(NB_MAX * 4);
    char* z1 = w;
    float* as1  = (float*)alloc((size_t)N * 4 * 4);
    float* ad1  = (float*)alloc((size_t)N * 4 * 4);
    float* as2  = (float*)alloc((size_t)N * 4);
    float* ad2  = (float*)alloc((size_t)N * 4);
    __half* uv = (__half*)alloc((size_t)N * 64 * 2);

    int zn4 = (int)((z1 - z0) / 16);
    zero_prep_kernel<<<112, 256, 0, stream>>>(W1, W2, Wm1, W1Th, W2Th, Wm1T,
                                              (uint4*)z0, zn4);

    int nbG = (N + 63) / 64;
    gemm1_passA_kernel<<<2 * nbG + nbA, 256, 0, stream>>>(
        x, W1Th, atS1, atD1, h1, as1, ad1, N, nbG,
        ei, ei + E, E, bktcnt, lbase_g, nbkt);

    scanb_kernel<<<1, 512, 0, stream>>>(bktcnt, bktoff, nbkt);
    passB_kernel<<<nbA, 256, 0, stream>>>(ei, ei + E, E, N, bktoff, lbase_g,
                                          ebuf, nbkt);
    build_kernel<<<nbkt, 256, 0, stream>>>(ebuf, bktoff, rowp, csrs, N, nbkt);

    edge1_kernel<<<(N + 3) / 4, 256, 0, stream>>>(csrs, rowp, (const __half2*)h1,
                                                  as1, ad1, b1, x2h, N);
    gemm2_kernel<<<nbG, 256, 0, stream>>>((const _Float16*)x2h, W2Th, atS2, atD2,
                                          h2, as2, ad2, N);
    edge2_kernel<<<(N + 3) / 4, 256, 0, stream>>>(csrs, rowp, (const __half*)h2,
                                                  as2, ad2, b2, hf, N);

    node_mlp_kernel<<<1024, 256, 0, stream>>>(hf, Wm1T, uv, N);
    pair_mlp_kernel<<<(2 * P + 255) / 256, 256, 0, stream>>>(ep, ep + P,
                                                             (const __half2*)uv,
                                                             bm1, Wm2, bm2, out, P);
}